// Round 8
// baseline (435.303 us; speedup 1.0000x reference)
//
#include <hip/hip_runtime.h>
#include <hip/hip_bf16.h>
#include <stdint.h>

#define NNODES 100000
#define NEDGES 600000

typedef __attribute__((ext_vector_type(8))) short bf16x8;
typedef __attribute__((ext_vector_type(4))) float f32x4;
typedef __attribute__((ext_vector_type(4))) unsigned int u32x4;

__device__ inline float b2f(short b) {
    union { unsigned u; float f; } v;
    v.u = ((unsigned)(unsigned short)b) << 16;
    return v.f;
}
__device__ inline short f2b(float f) {
    union { float f; unsigned u; } v;
    v.f = f;
    unsigned r = (v.u + 0x7FFFu + ((v.u >> 16) & 1u)) >> 16;
    return (short)r;
}
__device__ inline unsigned packbf(float lo, float hi) {
    return ((unsigned)(unsigned short)f2b(hi) << 16) | (unsigned)(unsigned short)f2b(lo);
}
#define MFMA16(a, b, c) __builtin_amdgcn_mfma_f32_16x16x32_bf16(a, b, c, 0, 0, 0)

// ---------------- fused prep ----------------
// zero pos/stats; x->bf16 (+zero row); weights -> bf16 packed per-fragment, ct-major:
// Wpk[ct][kt][lane][j] = W[k = kt*32 + (lane>>4)*8 + j][c = ct*16 + (lane&15)]
__global__ __launch_bounds__(256) void k_prep(const float* __restrict__ x,
                                              const float* __restrict__ W1,
                                              const float* __restrict__ W2,
                                              const float* __restrict__ Wm1,
                                              const float* __restrict__ Wm2,
                                              short* __restrict__ xb, short* __restrict__ Wt,
                                              int* __restrict__ pos, float* __restrict__ stats) {
    int i = blockIdx.x * 256 + threadIdx.x;
    if (i < (NNODES + 1) * 16) {
        bf16x8 o = (bf16x8){0, 0, 0, 0, 0, 0, 0, 0};
        if (i < NNODES * 16) {
            const float4* p = (const float4*)(x + (size_t)i * 8);
            float4 a = p[0], b = p[1];
            o[0] = f2b(a.x); o[1] = f2b(a.y); o[2] = f2b(a.z); o[3] = f2b(a.w);
            o[4] = f2b(b.x); o[5] = f2b(b.y); o[6] = f2b(b.z); o[7] = f2b(b.w);
        }
        *(bf16x8*)(xb + (size_t)i * 8) = o;
    }
    if (i < NNODES) pos[i] = 0;
    if (i < 57344) {
        int jj, lane, kt, ct;
        const float* W;
        int ldw, off;
        if (i < 16384) { off = i; W = W1; ldw = 128; }
        else if (i < 32768) { off = i - 16384; W = W2; ldw = 128; }
        else if (i < 49152) { off = i - 32768; W = Wm1; ldw = 128; }
        else { off = i - 49152; W = Wm2; ldw = 64; }
        jj = off & 7;
        lane = (off >> 3) & 63;
        kt = (off >> 9) & 3;
        ct = (off >> 11) & 7;  // for Wm2 only 0..3 occur (off < 8192)
        int lr = lane & 15, hi = lane >> 4;
        int c = ct * 16 + lr;
        int k = kt * 32 + hi * 8 + jj;
        Wt[i] = f2b(W[k * ldw + c]);
    }
    if (i < 256) stats[i] = 0.0f;
}

// ---------------- CSR build ----------------

__global__ __launch_bounds__(256) void k_hist(const int* __restrict__ ei, int* __restrict__ cnt) {
    int e = blockIdx.x * 256 + threadIdx.x;
    if (e < NEDGES) atomicAdd(&cnt[ei[NEDGES + e]], 1);
}

// single-block exclusive scan of 100000 counts (cnt may alias pos)
__global__ __launch_bounds__(1024) void k_scan(const int* __restrict__ cnt,
                                               int* __restrict__ rowptr, int* __restrict__ pos) {
    __shared__ int sd[1024];
    int t = threadIdx.x;
    int base = t * 98;
    int s = 0;
    for (int i = 0; i < 98; ++i) {
        int idx = base + i;
        if (idx < NNODES) s += cnt[idx];
    }
    sd[t] = s;
    __syncthreads();
    for (int off = 1; off < 1024; off <<= 1) {
        int v = (t >= off) ? sd[t - off] : 0;
        __syncthreads();
        sd[t] += v;
        __syncthreads();
    }
    int run = sd[t] - s;  // exclusive prefix
    for (int i = 0; i < 98; ++i) {
        int idx = base + i;
        if (idx < NNODES) {
            int v = cnt[idx];
            rowptr[idx] = run;
            pos[idx] = run;
            run += v;
        }
    }
    if (t == 1023) rowptr[NNODES] = run;
}

__global__ __launch_bounds__(256) void k_fill(const int* __restrict__ ei, int* __restrict__ pos,
                                              int* __restrict__ elist) {
    int e = blockIdx.x * 256 + threadIdx.x;
    if (e >= NEDGES) return;
    int src = ei[e];
    int dst = ei[NEDGES + e];
    int p = atomicAdd(&pos[dst], 1);
    elist[p] = src;
}

// ---------------- gather-aggregate ----------------
__global__ __launch_bounds__(256) void k_agg(const short* __restrict__ xb,
                                             const int* __restrict__ rowptr,
                                             const int* __restrict__ elist,
                                             short* __restrict__ bufb) {
    int t = threadIdx.x;
    int w = t >> 6, lane = t & 63;
    int node = blockIdx.x * 4 + w;
    if (node >= NNODES) return;
    int beg = rowptr[node];
    int end = rowptr[node + 1];
    int deg = end - beg;
    int total = deg + 1;
    int sub = lane & 31, half = lane >> 5;
    const uint2* xr = (const uint2*)xb;

    float acc0 = 0.f, acc1 = 0.f, acc2 = 0.f, acc3 = 0.f;

    for (int base = 0; base < total; base += 64) {
        int j = base + lane;
        int ej = NNODES;  // zero row
        if (j < total) ej = (j == 0) ? node : elist[beg + j - 1];
        int cnt = min(64, total - base);
        int pairs = (cnt + 1) >> 1;
        for (int i = 0; i < pairs; i += 4) {
            int j0 = 2 * i + half;
            int r0 = __shfl(ej, j0);
            int r1 = __shfl(ej, j0 + 2);
            int r2 = __shfl(ej, j0 + 4);
            int r3 = __shfl(ej, j0 + 6);
            uint2 v0 = xr[(size_t)r0 * 32 + sub];
            uint2 v1 = xr[(size_t)r1 * 32 + sub];
            uint2 v2 = xr[(size_t)r2 * 32 + sub];
            uint2 v3 = xr[(size_t)r3 * 32 + sub];
            acc0 += b2f((short)(v0.x & 0xFFFF)) + b2f((short)(v1.x & 0xFFFF)) +
                    b2f((short)(v2.x & 0xFFFF)) + b2f((short)(v3.x & 0xFFFF));
            acc1 += b2f((short)(v0.x >> 16)) + b2f((short)(v1.x >> 16)) +
                    b2f((short)(v2.x >> 16)) + b2f((short)(v3.x >> 16));
            acc2 += b2f((short)(v0.y & 0xFFFF)) + b2f((short)(v1.y & 0xFFFF)) +
                    b2f((short)(v2.y & 0xFFFF)) + b2f((short)(v3.y & 0xFFFF));
            acc3 += b2f((short)(v0.y >> 16)) + b2f((short)(v1.y >> 16)) +
                    b2f((short)(v2.y >> 16)) + b2f((short)(v3.y >> 16));
        }
    }
    acc0 += __shfl_xor(acc0, 32);
    acc1 += __shfl_xor(acc1, 32);
    acc2 += __shfl_xor(acc2, 32);
    acc3 += __shfl_xor(acc3, 32);
    if (half == 0) {
        uint2 o;
        o.x = ((uint32_t)(unsigned short)f2b(acc1) << 16) | (uint32_t)(unsigned short)f2b(acc0);
        o.y = ((uint32_t)(unsigned short)f2b(acc3) << 16) | (uint32_t)(unsigned short)f2b(acc2);
        ((uint2*)bufb)[(size_t)node * 32 + sub] = o;
    }
}

// ---------------- stats: u = agg @ W1 (b1 cancels in BN); S,Q per column ----------
__global__ __launch_bounds__(256) void k_stats(const short* __restrict__ bufb,
                                               const short* __restrict__ W1pk,
                                               float* __restrict__ stats) {
    __shared__ float Sred[2][4][128];
    int t = threadIdx.x, w = t >> 6, l = t & 63;
    int r0 = blockIdx.x * 128;
    int row0 = (w & 1) * 64, col0 = (w >> 1) * 64;

    f32x4 acc[4][4];
#pragma unroll
    for (int r = 0; r < 4; ++r)
#pragma unroll
        for (int c = 0; c < 4; ++c) acc[r][c] = (f32x4){0.f, 0.f, 0.f, 0.f};

#pragma unroll
    for (int kb = 0; kb < 4; ++kb) {
        bf16x8 af[4], bw[4];
#pragma unroll
        for (int r = 0; r < 4; ++r)
            af[r] = *(const bf16x8*)(bufb + (size_t)(r0 + row0 + r * 16 + (l & 15)) * 128 +
                                     kb * 32 + (l >> 4) * 8);
#pragma unroll
        for (int c = 0; c < 4; ++c)
            bw[c] = *(const bf16x8*)(W1pk + ((((w >> 1) * 4 + c) * 4 + kb) * 64 + l) * 8);
#pragma unroll
        for (int r = 0; r < 4; ++r)
#pragma unroll
            for (int c = 0; c < 4; ++c) acc[r][c] = MFMA16(af[r], bw[c], acc[r][c]);
    }

    float s[4], q[4];
#pragma unroll
    for (int c = 0; c < 4; ++c) { s[c] = 0.f; q[c] = 0.f; }
#pragma unroll
    for (int c = 0; c < 4; ++c)
#pragma unroll
        for (int r = 0; r < 4; ++r)
#pragma unroll
            for (int rr = 0; rr < 4; ++rr) {
                int grow = r0 + row0 + r * 16 + (l >> 4) * 4 + rr;
                if (grow < NNODES) {
                    float v = acc[r][c][rr];
                    s[c] += v;
                    q[c] += v * v;
                }
            }
#pragma unroll
    for (int c = 0; c < 4; ++c) {
        s[c] += __shfl_xor(s[c], 16); s[c] += __shfl_xor(s[c], 32);
        q[c] += __shfl_xor(q[c], 16); q[c] += __shfl_xor(q[c], 32);
    }
    if (l < 16) {
#pragma unroll
        for (int c = 0; c < 4; ++c) {
            Sred[0][w][col0 + c * 16 + l] = s[c];
            Sred[1][w][col0 + c * 16 + l] = q[c];
        }
    }
    __syncthreads();
    if (t < 128) {
        int wb = (t < 64) ? 0 : 2;
        atomicAdd(stats + t, Sred[0][wb][t] + Sred[0][wb + 1][t]);
        atomicAdd(stats + 128 + t, Sred[1][wb][t] + Sred[1][wb + 1][t]);
    }
}

// ---------------- fused MLP, zero activation-LDS ----------------
// G1..G3 operand-swapped: C[c][node] = mfma(W^T as A, act as B); node stays in lane&15.
// C -> next B via register pack + shuffles (shuffle BOTH ct candidates, select with
// DEST-side h2 after the pull — __shfl evaluates the value in the source lane).
// G4 swaps back for coalesced stores.
__global__ __launch_bounds__(256, 4) void k_mlp(const short* __restrict__ bufb,
                                                const float* __restrict__ stats,
                                                const float* __restrict__ gamma,
                                                const float* __restrict__ beta,
                                                const short* __restrict__ Wt,
                                                const float* __restrict__ b2,
                                                const float* __restrict__ bm1,
                                                const float* __restrict__ bm2,
                                                float* __restrict__ out) {
    __shared__ float scale[128], shift[128], b2s[128], bm1s[128], bm2s[64];

    int t = threadIdx.x, w = t >> 6, l = t & 63;
    int lr = l & 15, hi = l >> 4;
    size_t node0 = (size_t)blockIdx.x * 64 + w * 16;  // this wave's 16 nodes
    const short* W1pk = Wt;
    const short* W2pk = Wt + 16384;
    const short* Wm1pk = Wt + 32768;
    const short* Wm2pk = Wt + 49152;

    if (t < 128) {
        float mean = stats[t] * (1.0f / NNODES);
        float var = stats[128 + t] * (1.0f / NNODES) - mean * mean;
        var = fmaxf(var, 0.0f);
        float inv = rsqrtf(var + 1e-5f);
        float sc = gamma[t] * inv;
        scale[t] = sc;
        shift[t] = beta[t] - mean * sc;  // b1 cancels in batch-stats BN
        b2s[t] = b2[t];
        bm1s[t] = bm1[t];
    }
    if (t < 64) bm2s[t] = bm2[t];
    __syncthreads();

    // B-frags for G1 straight from global: bv[kt] = act[node=lr][k=kt*32+hi*8+j]
    bf16x8 bv[4];
#pragma unroll
    for (int kt = 0; kt < 4; ++kt)
        bv[kt] = *(const bf16x8*)(bufb + (node0 + lr) * 128 + kt * 32 + hi * 8);

    unsigned pw[8][2];  // packed C words: pw[ct][w] = channels ct*16+hi*4+2w+{0,1}, node lr

    // ---- G1: relu(BN(agg @ W1)) ----
#pragma unroll
    for (int ct = 0; ct < 8; ++ct) {
        f32x4 a = (f32x4){0.f, 0.f, 0.f, 0.f};
#pragma unroll
        for (int kt = 0; kt < 4; ++kt)
            a = MFMA16(*(const bf16x8*)(W1pk + ((ct * 4 + kt) * 64 + l) * 8), bv[kt], a);
        int c0 = ct * 16 + hi * 4;
        float4 sc4 = *(const float4*)&scale[c0];
        float4 sh4 = *(const float4*)&shift[c0];
        float v0 = fmaxf(a[0] * sc4.x + sh4.x, 0.f);
        float v1 = fmaxf(a[1] * sc4.y + sh4.y, 0.f);
        float v2 = fmaxf(a[2] * sc4.z + sh4.z, 0.f);
        float v3 = fmaxf(a[3] * sc4.w + sh4.w, 0.f);
        pw[ct][0] = packbf(v0, v1);
        pw[ct][1] = packbf(v2, v3);
    }

    // redistribute pw -> bv: target elem j of bv[kt] = channel kt*32+hi*8+j, node lr.
    // src: ct_src = 2kt + h2_dest, lane (2*h1_dest + (j>>2))*16 + lr, word (j>>1)&1.
    // Shuffle both ct candidates (lane-uniform regs), select with dest h2 afterwards.
#define REDIST()                                                                        \
    {                                                                                   \
        int h2 = hi >> 1, h1 = hi & 1;                                                  \
        _Pragma("unroll") for (int kt = 0; kt < 4; ++kt) {                              \
            unsigned nw[4];                                                             \
            _Pragma("unroll") for (int jp = 0; jp < 4; ++jp) {                          \
                int srcl = (2 * h1 + (jp >> 1)) * 16 + lr;                              \
                unsigned ve = (unsigned)__shfl((int)pw[2 * kt][jp & 1], srcl);          \
                unsigned vo = (unsigned)__shfl((int)pw[2 * kt + 1][jp & 1], srcl);      \
                nw[jp] = h2 ? vo : ve;                                                  \
            }                                                                           \
            u32x4 uq = (u32x4){nw[0], nw[1], nw[2], nw[3]};                             \
            bv[kt] = __builtin_bit_cast(bf16x8, uq);                                    \
        }                                                                               \
    }
    REDIST();

    // ---- G2: relu(h @ W2 + b2) ----
#pragma unroll
    for (int ct = 0; ct < 8; ++ct) {
        f32x4 a = (f32x4){0.f, 0.f, 0.f, 0.f};
#pragma unroll
        for (int kt = 0; kt < 4; ++kt)
            a = MFMA16(*(const bf16x8*)(W2pk + ((ct * 4 + kt) * 64 + l) * 8), bv[kt], a);
        int c0 = ct * 16 + hi * 4;
        float4 bb = *(const float4*)&b2s[c0];
        float v0 = fmaxf(a[0] + bb.x, 0.f);
        float v1 = fmaxf(a[1] + bb.y, 0.f);
        float v2 = fmaxf(a[2] + bb.z, 0.f);
        float v3 = fmaxf(a[3] + bb.w, 0.f);
        pw[ct][0] = packbf(v0, v1);
        pw[ct][1] = packbf(v2, v3);
    }
    REDIST();

    // ---- G3: relu(h @ Wm1 + bm1) ----
#pragma unroll
    for (int ct = 0; ct < 8; ++ct) {
        f32x4 a = (f32x4){0.f, 0.f, 0.f, 0.f};
#pragma unroll
        for (int kt = 0; kt < 4; ++kt)
            a = MFMA16(*(const bf16x8*)(Wm1pk + ((ct * 4 + kt) * 64 + l) * 8), bv[kt], a);
        int c0 = ct * 16 + hi * 4;
        float4 bb = *(const float4*)&bm1s[c0];
        float v0 = fmaxf(a[0] + bb.x, 0.f);
        float v1 = fmaxf(a[1] + bb.y, 0.f);
        float v2 = fmaxf(a[2] + bb.z, 0.f);
        float v3 = fmaxf(a[3] + bb.w, 0.f);
        pw[ct][0] = packbf(v0, v1);
        pw[ct][1] = packbf(v2, v3);
    }
    REDIST();

    // ---- G4: h @ Wm2 + bm2 -> out (bv doubles as A-frags: same lane layout) ----
#pragma unroll
    for (int ct = 0; ct < 4; ++ct) {
        f32x4 a = (f32x4){0.f, 0.f, 0.f, 0.f};
#pragma unroll
        for (int kt = 0; kt < 4; ++kt)
            a = MFMA16(bv[kt], *(const bf16x8*)(Wm2pk + ((ct * 4 + kt) * 64 + l) * 8), a);
        float bias = bm2s[ct * 16 + lr];
#pragma unroll
        for (int rr = 0; rr < 4; ++rr) {
            size_t grow = node0 + hi * 4 + rr;
            if (grow < NNODES) out[grow * 64 + ct * 16 + lr] = a[rr] + bias;
        }
    }
}

// ---------------- launch ----------------
extern "C" void kernel_launch(void* const* d_in, const int* in_sizes, int n_in,
                              void* d_out, int out_size, void* d_ws, size_t ws_size,
                              hipStream_t stream) {
    const float* x     = (const float*)d_in[0];
    const int*   ei    = (const int*)d_in[1];
    const float* W1    = (const float*)d_in[2];
    const float* gamma = (const float*)d_in[4];
    const float* beta  = (const float*)d_in[5];
    const float* W2    = (const float*)d_in[6];
    const float* b2    = (const float*)d_in[7];
    const float* Wm1   = (const float*)d_in[8];
    const float* bm1   = (const float*)d_in[9];
    const float* Wm2   = (const float*)d_in[10];
    const float* bm2   = (const float*)d_in[11];
    float* out = (float*)d_out;

    char* ws = (char*)d_ws;
    short* xb    = (short*)ws;                           // (N+1)*128 bf16 (last row zeros)
    short* bufb  = xb + (size_t)(NNODES + 1) * 128;      // (N+128)*128 bf16 (tail padding)
    short* Wt    = bufb + (size_t)(NNODES + 128) * 128;  // 57344 bf16 packed fragments
    float* stats = (float*)(Wt + 57344);                 // 256 f32
    int* rowptr  = (int*)(stats + 256);                  // N+1
    int* pos     = rowptr + (NNODES + 1);                // N
    int* elist   = pos + NNODES;                         // E

    int gE = (NEDGES + 255) / 256;
    int gPrep = ((NNODES + 1) * 16 + 255) / 256;

    k_prep<<<gPrep, 256, 0, stream>>>(x, W1, W2, Wm1, Wm2, xb, Wt, pos, stats);
    k_hist<<<gE, 256, 0, stream>>>(ei, pos);
    k_scan<<<1, 1024, 0, stream>>>(pos, rowptr, pos);
    k_fill<<<gE, 256, 0, stream>>>(ei, pos, elist);
    k_agg<<<(NNODES + 3) / 4, 256, 0, stream>>>(xb, rowptr, elist, bufb);

    int nblkS = (NNODES + 127) / 128;
    k_stats<<<nblkS, 256, 0, stream>>>(bufb, Wt, stats);
    int nblkM = (NNODES + 63) / 64;
    k_mlp<<<nblkM, 256, 0, stream>>>(bufb, stats, gamma, beta, Wt, b2, bm1, bm2, out);
}

// Round 9
// 190.621 us; speedup vs baseline: 2.2836x; 2.2836x over previous
//
#include <hip/hip_runtime.h>
#include <hip/hip_bf16.h>
#include <stdint.h>

#define NNODES 100000
#define NEDGES 600000
#define SCAN_CHUNK 1024
#define SCAN_NB 98  // ceil(100000/1024)

typedef __attribute__((ext_vector_type(8))) short bf16x8;
typedef __attribute__((ext_vector_type(4))) float f32x4;
typedef __attribute__((ext_vector_type(4))) unsigned int u32x4;

__device__ inline float b2f(short b) {
    union { unsigned u; float f; } v;
    v.u = ((unsigned)(unsigned short)b) << 16;
    return v.f;
}
__device__ inline short f2b(float f) {
    union { float f; unsigned u; } v;
    v.f = f;
    unsigned r = (v.u + 0x7FFFu + ((v.u >> 16) & 1u)) >> 16;
    return (short)r;
}
__device__ inline unsigned packbf(float lo, float hi) {
    return ((unsigned)(unsigned short)f2b(hi) << 16) | (unsigned)(unsigned short)f2b(lo);
}
#define MFMA16(a, b, c) __builtin_amdgcn_mfma_f32_16x16x32_bf16(a, b, c, 0, 0, 0)

// ---------------- fused prep ----------------
// zero pos/stats; x->bf16 (+zero row); weights -> bf16 packed per-fragment, ct-major:
// Wpk[ct][kt][lane][j] = W[k = kt*32 + (lane>>4)*8 + j][c = ct*16 + (lane&15)]
__global__ __launch_bounds__(256) void k_prep(const float* __restrict__ x,
                                              const float* __restrict__ W1,
                                              const float* __restrict__ W2,
                                              const float* __restrict__ Wm1,
                                              const float* __restrict__ Wm2,
                                              short* __restrict__ xb, short* __restrict__ Wt,
                                              int* __restrict__ pos, float* __restrict__ stats) {
    int i = blockIdx.x * 256 + threadIdx.x;
    if (i < (NNODES + 1) * 16) {
        bf16x8 o = (bf16x8){0, 0, 0, 0, 0, 0, 0, 0};
        if (i < NNODES * 16) {
            const float4* p = (const float4*)(x + (size_t)i * 8);
            float4 a = p[0], b = p[1];
            o[0] = f2b(a.x); o[1] = f2b(a.y); o[2] = f2b(a.z); o[3] = f2b(a.w);
            o[4] = f2b(b.x); o[5] = f2b(b.y); o[6] = f2b(b.z); o[7] = f2b(b.w);
        }
        *(bf16x8*)(xb + (size_t)i * 8) = o;
    }
    if (i < NNODES) pos[i] = 0;
    if (i < 57344) {
        int jj, lane, kt, ct;
        const float* W;
        int ldw, off;
        if (i < 16384) { off = i; W = W1; ldw = 128; }
        else if (i < 32768) { off = i - 16384; W = W2; ldw = 128; }
        else if (i < 49152) { off = i - 32768; W = Wm1; ldw = 128; }
        else { off = i - 49152; W = Wm2; ldw = 64; }
        jj = off & 7;
        lane = (off >> 3) & 63;
        kt = (off >> 9) & 3;
        ct = (off >> 11) & 7;  // for Wm2 only 0..3 occur (off < 8192)
        int lr = lane & 15, hi = lane >> 4;
        int c = ct * 16 + lr;
        int k = kt * 32 + hi * 8 + jj;
        Wt[i] = f2b(W[k * ldw + c]);
    }
    if (i < 256) stats[i] = 0.0f;
}

// ---------------- CSR build ----------------

__global__ __launch_bounds__(256) void k_hist(const int* __restrict__ ei, int* __restrict__ cnt) {
    int e = blockIdx.x * 256 + threadIdx.x;
    if (e < NEDGES) atomicAdd(&cnt[ei[NEDGES + e]], 1);
}

// per-block sums of 1024 counts
__global__ __launch_bounds__(256) void k_scan1(const int* __restrict__ cnt, int* __restrict__ bsums) {
    __shared__ int sd[256];
    int b = blockIdx.x, t = threadIdx.x;
    int base = b * SCAN_CHUNK + t * 4;
    int s = 0;
#pragma unroll
    for (int i = 0; i < 4; ++i) {
        int idx = base + i;
        if (idx < NNODES) s += cnt[idx];
    }
    sd[t] = s;
    __syncthreads();
    for (int off = 128; off > 0; off >>= 1) {
        if (t < off) sd[t] += sd[t + off];
        __syncthreads();
    }
    if (t == 0) bsums[b] = sd[0];
}

// serial scan of 98 block sums (tiny)
__global__ __launch_bounds__(64) void k_scan2(int* __restrict__ bsums, int* __restrict__ rowptr) {
    if (threadIdx.x == 0 && blockIdx.x == 0) {
        int run = 0;
        for (int b = 0; b < SCAN_NB; ++b) {
            int v = bsums[b];
            bsums[b] = run;
            run += v;
        }
        rowptr[NNODES] = run;
    }
}

// full exclusive scan: rowptr[i] and pos[i] (fill cursor). cnt and pos may alias.
__global__ __launch_bounds__(256) void k_scan3(const int* __restrict__ cnt,
                                               const int* __restrict__ bsums,
                                               int* __restrict__ rowptr, int* __restrict__ pos) {
    __shared__ int sd[256];
    int b = blockIdx.x, t = threadIdx.x;
    int base = b * SCAN_CHUNK + t * 4;
    int v[4];
    int s = 0;
#pragma unroll
    for (int i = 0; i < 4; ++i) {
        int idx = base + i;
        v[i] = (idx < NNODES) ? cnt[idx] : 0;
        s += v[i];
    }
    sd[t] = s;
    __syncthreads();
    for (int off = 1; off < 256; off <<= 1) {
        int val = (t >= off) ? sd[t - off] : 0;
        __syncthreads();
        sd[t] += val;
        __syncthreads();
    }
    int run = sd[t] - s + bsums[b];
#pragma unroll
    for (int i = 0; i < 4; ++i) {
        int idx = base + i;
        if (idx < NNODES) {
            rowptr[idx] = run;
            pos[idx] = run;
            run += v[i];
        }
    }
}

__global__ __launch_bounds__(256) void k_fill(const int* __restrict__ ei, int* __restrict__ pos,
                                              int* __restrict__ elist) {
    int e = blockIdx.x * 256 + threadIdx.x;
    if (e >= NEDGES) return;
    int src = ei[e];
    int dst = ei[NEDGES + e];
    int p = atomicAdd(&pos[dst], 1);
    elist[p] = src;
}

// ---------------- gather-aggregate ----------------
__global__ __launch_bounds__(256) void k_agg(const short* __restrict__ xb,
                                             const int* __restrict__ rowptr,
                                             const int* __restrict__ elist,
                                             short* __restrict__ bufb) {
    int t = threadIdx.x;
    int w = t >> 6, lane = t & 63;
    int node = blockIdx.x * 4 + w;
    if (node >= NNODES) return;
    int beg = rowptr[node];
    int end = rowptr[node + 1];
    int deg = end - beg;
    int total = deg + 1;
    int sub = lane & 31, half = lane >> 5;
    const uint2* xr = (const uint2*)xb;

    float acc0 = 0.f, acc1 = 0.f, acc2 = 0.f, acc3 = 0.f;

    for (int base = 0; base < total; base += 64) {
        int j = base + lane;
        int ej = NNODES;  // zero row
        if (j < total) ej = (j == 0) ? node : elist[beg + j - 1];
        int cnt = min(64, total - base);
        int pairs = (cnt + 1) >> 1;
        for (int i = 0; i < pairs; i += 4) {
            int j0 = 2 * i + half;
            int r0 = __shfl(ej, j0);
            int r1 = __shfl(ej, j0 + 2);
            int r2 = __shfl(ej, j0 + 4);
            int r3 = __shfl(ej, j0 + 6);
            uint2 v0 = xr[(size_t)r0 * 32 + sub];
            uint2 v1 = xr[(size_t)r1 * 32 + sub];
            uint2 v2 = xr[(size_t)r2 * 32 + sub];
            uint2 v3 = xr[(size_t)r3 * 32 + sub];
            acc0 += b2f((short)(v0.x & 0xFFFF)) + b2f((short)(v1.x & 0xFFFF)) +
                    b2f((short)(v2.x & 0xFFFF)) + b2f((short)(v3.x & 0xFFFF));
            acc1 += b2f((short)(v0.x >> 16)) + b2f((short)(v1.x >> 16)) +
                    b2f((short)(v2.x >> 16)) + b2f((short)(v3.x >> 16));
            acc2 += b2f((short)(v0.y & 0xFFFF)) + b2f((short)(v1.y & 0xFFFF)) +
                    b2f((short)(v2.y & 0xFFFF)) + b2f((short)(v3.y & 0xFFFF));
            acc3 += b2f((short)(v0.y >> 16)) + b2f((short)(v1.y >> 16)) +
                    b2f((short)(v2.y >> 16)) + b2f((short)(v3.y >> 16));
        }
    }
    acc0 += __shfl_xor(acc0, 32);
    acc1 += __shfl_xor(acc1, 32);
    acc2 += __shfl_xor(acc2, 32);
    acc3 += __shfl_xor(acc3, 32);
    if (half == 0) {
        uint2 o;
        o.x = ((uint32_t)(unsigned short)f2b(acc1) << 16) | (uint32_t)(unsigned short)f2b(acc0);
        o.y = ((uint32_t)(unsigned short)f2b(acc3) << 16) | (uint32_t)(unsigned short)f2b(acc2);
        ((uint2*)bufb)[(size_t)node * 32 + sub] = o;
    }
}

// ---------------- stats: u = agg @ W1 (b1 cancels in BN); S,Q per column ----------
__global__ __launch_bounds__(256) void k_stats(const short* __restrict__ bufb,
                                               const short* __restrict__ W1pk,
                                               float* __restrict__ stats) {
    __shared__ float Sred[2][4][128];
    int t = threadIdx.x, w = t >> 6, l = t & 63;
    int r0 = blockIdx.x * 128;
    int row0 = (w & 1) * 64, col0 = (w >> 1) * 64;

    f32x4 acc[4][4];
#pragma unroll
    for (int r = 0; r < 4; ++r)
#pragma unroll
        for (int c = 0; c < 4; ++c) acc[r][c] = (f32x4){0.f, 0.f, 0.f, 0.f};

#pragma unroll
    for (int kb = 0; kb < 4; ++kb) {
        bf16x8 af[4], bw[4];
#pragma unroll
        for (int r = 0; r < 4; ++r)
            af[r] = *(const bf16x8*)(bufb + (size_t)(r0 + row0 + r * 16 + (l & 15)) * 128 +
                                     kb * 32 + (l >> 4) * 8);
#pragma unroll
        for (int c = 0; c < 4; ++c)
            bw[c] = *(const bf16x8*)(W1pk + ((((w >> 1) * 4 + c) * 4 + kb) * 64 + l) * 8);
#pragma unroll
        for (int r = 0; r < 4; ++r)
#pragma unroll
            for (int c = 0; c < 4; ++c) acc[r][c] = MFMA16(af[r], bw[c], acc[r][c]);
    }

    float s[4], q[4];
#pragma unroll
    for (int c = 0; c < 4; ++c) { s[c] = 0.f; q[c] = 0.f; }
#pragma unroll
    for (int c = 0; c < 4; ++c)
#pragma unroll
        for (int r = 0; r < 4; ++r)
#pragma unroll
            for (int rr = 0; rr < 4; ++rr) {
                int grow = r0 + row0 + r * 16 + (l >> 4) * 4 + rr;
                if (grow < NNODES) {
                    float v = acc[r][c][rr];
                    s[c] += v;
                    q[c] += v * v;
                }
            }
#pragma unroll
    for (int c = 0; c < 4; ++c) {
        s[c] += __shfl_xor(s[c], 16); s[c] += __shfl_xor(s[c], 32);
        q[c] += __shfl_xor(q[c], 16); q[c] += __shfl_xor(q[c], 32);
    }
    if (l < 16) {
#pragma unroll
        for (int c = 0; c < 4; ++c) {
            Sred[0][w][col0 + c * 16 + l] = s[c];
            Sred[1][w][col0 + c * 16 + l] = q[c];
        }
    }
    __syncthreads();
    if (t < 128) {
        int wb = (t < 64) ? 0 : 2;
        atomicAdd(stats + t, Sred[0][wb][t] + Sred[0][wb + 1][t]);
        atomicAdd(stats + 128 + t, Sred[1][wb][t] + Sred[1][wb + 1][t]);
    }
}

// ---------------- fused MLP, zero activation-LDS ----------------
// G1..G3 operand-swapped: C[c][node] = mfma(W^T as A, act as B); node stays in lane&15.
// C -> next B via register pack + shuffles (shuffle BOTH ct candidates, select with
// DEST-side h2 after the pull — __shfl evaluates the value in the source lane).
// G4 swaps back for coalesced stores.
__global__ __launch_bounds__(256, 4) void k_mlp(const short* __restrict__ bufb,
                                                const float* __restrict__ stats,
                                                const float* __restrict__ gamma,
                                                const float* __restrict__ beta,
                                                const short* __restrict__ Wt,
                                                const float* __restrict__ b2,
                                                const float* __restrict__ bm1,
                                                const float* __restrict__ bm2,
                                                float* __restrict__ out) {
    __shared__ float scale[128], shift[128], b2s[128], bm1s[128], bm2s[64];

    int t = threadIdx.x, w = t >> 6, l = t & 63;
    int lr = l & 15, hi = l >> 4;
    size_t node0 = (size_t)blockIdx.x * 64 + w * 16;  // this wave's 16 nodes
    const short* W1pk = Wt;
    const short* W2pk = Wt + 16384;
    const short* Wm1pk = Wt + 32768;
    const short* Wm2pk = Wt + 49152;

    if (t < 128) {
        float mean = stats[t] * (1.0f / NNODES);
        float var = stats[128 + t] * (1.0f / NNODES) - mean * mean;
        var = fmaxf(var, 0.0f);
        float inv = rsqrtf(var + 1e-5f);
        float sc = gamma[t] * inv;
        scale[t] = sc;
        shift[t] = beta[t] - mean * sc;  // b1 cancels in batch-stats BN
        b2s[t] = b2[t];
        bm1s[t] = bm1[t];
    }
    if (t < 64) bm2s[t] = bm2[t];
    __syncthreads();

    // B-frags for G1 straight from global: bv[kt] = act[node=lr][k=kt*32+hi*8+j]
    bf16x8 bv[4];
#pragma unroll
    for (int kt = 0; kt < 4; ++kt)
        bv[kt] = *(const bf16x8*)(bufb + (node0 + lr) * 128 + kt * 32 + hi * 8);

    unsigned pw[8][2];  // packed C words: pw[ct][w] = channels ct*16+hi*4+2w+{0,1}, node lr

    // ---- G1: relu(BN(agg @ W1)) ----
#pragma unroll
    for (int ct = 0; ct < 8; ++ct) {
        f32x4 a = (f32x4){0.f, 0.f, 0.f, 0.f};
#pragma unroll
        for (int kt = 0; kt < 4; ++kt)
            a = MFMA16(*(const bf16x8*)(W1pk + ((ct * 4 + kt) * 64 + l) * 8), bv[kt], a);
        int c0 = ct * 16 + hi * 4;
        float4 sc4 = *(const float4*)&scale[c0];
        float4 sh4 = *(const float4*)&shift[c0];
        float v0 = fmaxf(a[0] * sc4.x + sh4.x, 0.f);
        float v1 = fmaxf(a[1] * sc4.y + sh4.y, 0.f);
        float v2 = fmaxf(a[2] * sc4.z + sh4.z, 0.f);
        float v3 = fmaxf(a[3] * sc4.w + sh4.w, 0.f);
        pw[ct][0] = packbf(v0, v1);
        pw[ct][1] = packbf(v2, v3);
    }

    // redistribute pw -> bv: target elem j of bv[kt] = channel kt*32+hi*8+j, node lr.
    // src: ct_src = 2kt + h2_dest, lane (2*h1_dest + (j>>2))*16 + lr, word (j>>1)&1.
    // Shuffle both ct candidates (lane-uniform regs), select with dest h2 afterwards.
#define REDIST()                                                                        \
    {                                                                                   \
        int h2 = hi >> 1, h1 = hi & 1;                                                  \
        _Pragma("unroll") for (int kt = 0; kt < 4; ++kt) {                              \
            unsigned nw[4];                                                             \
            _Pragma("unroll") for (int jp = 0; jp < 4; ++jp) {                          \
                int srcl = (2 * h1 + (jp >> 1)) * 16 + lr;                              \
                unsigned ve = (unsigned)__shfl((int)pw[2 * kt][jp & 1], srcl);          \
                unsigned vo = (unsigned)__shfl((int)pw[2 * kt + 1][jp & 1], srcl);      \
                nw[jp] = h2 ? vo : ve;                                                  \
            }                                                                           \
            u32x4 uq = (u32x4){nw[0], nw[1], nw[2], nw[3]};                             \
            bv[kt] = __builtin_bit_cast(bf16x8, uq);                                    \
        }                                                                               \
    }
    REDIST();

    // ---- G2: relu(h @ W2 + b2) ----
#pragma unroll
    for (int ct = 0; ct < 8; ++ct) {
        f32x4 a = (f32x4){0.f, 0.f, 0.f, 0.f};
#pragma unroll
        for (int kt = 0; kt < 4; ++kt)
            a = MFMA16(*(const bf16x8*)(W2pk + ((ct * 4 + kt) * 64 + l) * 8), bv[kt], a);
        int c0 = ct * 16 + hi * 4;
        float4 bb = *(const float4*)&b2s[c0];
        float v0 = fmaxf(a[0] + bb.x, 0.f);
        float v1 = fmaxf(a[1] + bb.y, 0.f);
        float v2 = fmaxf(a[2] + bb.z, 0.f);
        float v3 = fmaxf(a[3] + bb.w, 0.f);
        pw[ct][0] = packbf(v0, v1);
        pw[ct][1] = packbf(v2, v3);
    }
    REDIST();

    // ---- G3: relu(h @ Wm1 + bm1) ----
#pragma unroll
    for (int ct = 0; ct < 8; ++ct) {
        f32x4 a = (f32x4){0.f, 0.f, 0.f, 0.f};
#pragma unroll
        for (int kt = 0; kt < 4; ++kt)
            a = MFMA16(*(const bf16x8*)(Wm1pk + ((ct * 4 + kt) * 64 + l) * 8), bv[kt], a);
        int c0 = ct * 16 + hi * 4;
        float4 bb = *(const float4*)&bm1s[c0];
        float v0 = fmaxf(a[0] + bb.x, 0.f);
        float v1 = fmaxf(a[1] + bb.y, 0.f);
        float v2 = fmaxf(a[2] + bb.z, 0.f);
        float v3 = fmaxf(a[3] + bb.w, 0.f);
        pw[ct][0] = packbf(v0, v1);
        pw[ct][1] = packbf(v2, v3);
    }
    REDIST();

    // ---- G4: h @ Wm2 + bm2 -> out (bv doubles as A-frags: same lane layout) ----
#pragma unroll
    for (int ct = 0; ct < 4; ++ct) {
        f32x4 a = (f32x4){0.f, 0.f, 0.f, 0.f};
#pragma unroll
        for (int kt = 0; kt < 4; ++kt)
            a = MFMA16(bv[kt], *(const bf16x8*)(Wm2pk + ((ct * 4 + kt) * 64 + l) * 8), a);
        float bias = bm2s[ct * 16 + lr];
#pragma unroll
        for (int rr = 0; rr < 4; ++rr) {
            size_t grow = node0 + hi * 4 + rr;
            if (grow < NNODES) out[grow * 64 + ct * 16 + lr] = a[rr] + bias;
        }
    }
}

// ---------------- launch ----------------
extern "C" void kernel_launch(void* const* d_in, const int* in_sizes, int n_in,
                              void* d_out, int out_size, void* d_ws, size_t ws_size,
                              hipStream_t stream) {
    const float* x     = (const float*)d_in[0];
    const int*   ei    = (const int*)d_in[1];
    const float* W1    = (const float*)d_in[2];
    const float* gamma = (const float*)d_in[4];
    const float* beta  = (const float*)d_in[5];
    const float* W2    = (const float*)d_in[6];
    const float* b2    = (const float*)d_in[7];
    const float* Wm1   = (const float*)d_in[8];
    const float* bm1   = (const float*)d_in[9];
    const float* Wm2   = (const float*)d_in[10];
    const float* bm2   = (const float*)d_in[11];
    float* out = (float*)d_out;

    char* ws = (char*)d_ws;
    short* xb    = (short*)ws;                           // (N+1)*128 bf16 (last row zeros)
    short* bufb  = xb + (size_t)(NNODES + 1) * 128;      // (N+128)*128 bf16 (tail padding)
    short* Wt    = bufb + (size_t)(NNODES + 128) * 128;  // 57344 bf16 packed fragments
    float* stats = (float*)(Wt + 57344);                 // 256 f32
    int* rowptr  = (int*)(stats + 256);                  // N+1
    int* pos     = rowptr + (NNODES + 1);                // N
    int* elist   = pos + NNODES;                         // E
    int* bsums   = elist + NEDGES;                       // 128

    int gE = (NEDGES + 255) / 256;
    int gPrep = ((NNODES + 1) * 16 + 255) / 256;

    k_prep<<<gPrep, 256, 0, stream>>>(x, W1, W2, Wm1, Wm2, xb, Wt, pos, stats);
    k_hist<<<gE, 256, 0, stream>>>(ei, pos);
    k_scan1<<<SCAN_NB, 256, 0, stream>>>(pos, bsums);
    k_scan2<<<1, 64, 0, stream>>>(bsums, rowptr);
    k_scan3<<<SCAN_NB, 256, 0, stream>>>(pos, bsums, rowptr, pos);
    k_fill<<<gE, 256, 0, stream>>>(ei, pos, elist);
    k_agg<<<(NNODES + 3) / 4, 256, 0, stream>>>(xb, rowptr, elist, bufb);

    int nblkS = (NNODES + 127) / 128;
    k_stats<<<nblkS, 256, 0, stream>>>(bufb, Wt, stats);
    int nblkM = (NNODES + 63) / 64;
    k_mlp<<<nblkM, 256, 0, stream>>>(bufb, stats, gamma, beta, Wt, b2, bm1, bm2, out);
}

// Round 10
// 172.485 us; speedup vs baseline: 2.5237x; 1.1051x over previous
//
#include <hip/hip_runtime.h>
#include <hip/hip_bf16.h>
#include <stdint.h>

#define NNODES 100000
#define NEDGES 600000
#define SCAN_CHUNK 1024
#define SCAN_NB 98  // ceil(100000/1024)

typedef __attribute__((ext_vector_type(8))) short bf16x8;
typedef __attribute__((ext_vector_type(4))) float f32x4;
typedef __attribute__((ext_vector_type(4))) unsigned int u32x4;

__device__ inline float b2f(short b) {
    union { unsigned u; float f; } v;
    v.u = ((unsigned)(unsigned short)b) << 16;
    return v.f;
}
__device__ inline short f2b(float f) {
    union { float f; unsigned u; } v;
    v.f = f;
    unsigned r = (v.u + 0x7FFFu + ((v.u >> 16) & 1u)) >> 16;
    return (short)r;
}
__device__ inline unsigned packbf(float lo, float hi) {
    return ((unsigned)(unsigned short)f2b(hi) << 16) | (unsigned)(unsigned short)f2b(lo);
}
#define MFMA16(a, b, c) __builtin_amdgcn_mfma_f32_16x16x32_bf16(a, b, c, 0, 0, 0)

// ---------------- fused prep ----------------
// zero pos/stats; x->bf16 (+zero row); weights -> bf16 packed per-fragment, ct-major:
// Wpk[ct][kt][lane][j] = W[k = kt*32 + (lane>>4)*8 + j][c = ct*16 + (lane&15)]
__global__ __launch_bounds__(256) void k_prep(const float* __restrict__ x,
                                              const float* __restrict__ W1,
                                              const float* __restrict__ W2,
                                              const float* __restrict__ Wm1,
                                              const float* __restrict__ Wm2,
                                              short* __restrict__ xb, short* __restrict__ Wt,
                                              int* __restrict__ pos, float* __restrict__ stats) {
    int i = blockIdx.x * 256 + threadIdx.x;
    if (i < (NNODES + 1) * 16) {
        bf16x8 o = (bf16x8){0, 0, 0, 0, 0, 0, 0, 0};
        if (i < NNODES * 16) {
            const float4* p = (const float4*)(x + (size_t)i * 8);
            float4 a = p[0], b = p[1];
            o[0] = f2b(a.x); o[1] = f2b(a.y); o[2] = f2b(a.z); o[3] = f2b(a.w);
            o[4] = f2b(b.x); o[5] = f2b(b.y); o[6] = f2b(b.z); o[7] = f2b(b.w);
        }
        *(bf16x8*)(xb + (size_t)i * 8) = o;
    }
    if (i < NNODES) pos[i] = 0;
    if (i < 57344) {
        int jj, lane, kt, ct;
        const float* W;
        int ldw, off;
        if (i < 16384) { off = i; W = W1; ldw = 128; }
        else if (i < 32768) { off = i - 16384; W = W2; ldw = 128; }
        else if (i < 49152) { off = i - 32768; W = Wm1; ldw = 128; }
        else { off = i - 49152; W = Wm2; ldw = 64; }
        jj = off & 7;
        lane = (off >> 3) & 63;
        kt = (off >> 9) & 3;
        ct = (off >> 11) & 7;  // for Wm2 only 0..3 occur (off < 8192)
        int lr = lane & 15, hi = lane >> 4;
        int c = ct * 16 + lr;
        int k = kt * 32 + hi * 8 + jj;
        Wt[i] = f2b(W[k * ldw + c]);
    }
    if (i < 256) stats[i] = 0.0f;
}

// ---------------- CSR build ----------------

__global__ __launch_bounds__(256) void k_hist(const int* __restrict__ ei, int* __restrict__ cnt) {
    int e = blockIdx.x * 256 + threadIdx.x;
    if (e < NEDGES) atomicAdd(&cnt[ei[NEDGES + e]], 1);
}

// per-block sums of 1024 counts
__global__ __launch_bounds__(256) void k_scan1(const int* __restrict__ cnt, int* __restrict__ bsums) {
    __shared__ int sd[256];
    int b = blockIdx.x, t = threadIdx.x;
    int base = b * SCAN_CHUNK + t * 4;
    int s = 0;
#pragma unroll
    for (int i = 0; i < 4; ++i) {
        int idx = base + i;
        if (idx < NNODES) s += cnt[idx];
    }
    sd[t] = s;
    __syncthreads();
    for (int off = 128; off > 0; off >>= 1) {
        if (t < off) sd[t] += sd[t + off];
        __syncthreads();
    }
    if (t == 0) bsums[b] = sd[0];
}

// serial scan of 98 block sums (tiny)
__global__ __launch_bounds__(64) void k_scan2(int* __restrict__ bsums, int* __restrict__ rowptr) {
    if (threadIdx.x == 0 && blockIdx.x == 0) {
        int run = 0;
        for (int b = 0; b < SCAN_NB; ++b) {
            int v = bsums[b];
            bsums[b] = run;
            run += v;
        }
        rowptr[NNODES] = run;
    }
}

// full exclusive scan: rowptr[i] and pos[i] (fill cursor). cnt and pos may alias.
__global__ __launch_bounds__(256) void k_scan3(const int* __restrict__ cnt,
                                               const int* __restrict__ bsums,
                                               int* __restrict__ rowptr, int* __restrict__ pos) {
    __shared__ int sd[256];
    int b = blockIdx.x, t = threadIdx.x;
    int base = b * SCAN_CHUNK + t * 4;
    int v[4];
    int s = 0;
#pragma unroll
    for (int i = 0; i < 4; ++i) {
        int idx = base + i;
        v[i] = (idx < NNODES) ? cnt[idx] : 0;
        s += v[i];
    }
    sd[t] = s;
    __syncthreads();
    for (int off = 1; off < 256; off <<= 1) {
        int val = (t >= off) ? sd[t - off] : 0;
        __syncthreads();
        sd[t] += val;
        __syncthreads();
    }
    int run = sd[t] - s + bsums[b];
#pragma unroll
    for (int i = 0; i < 4; ++i) {
        int idx = base + i;
        if (idx < NNODES) {
            rowptr[idx] = run;
            pos[idx] = run;
            run += v[i];
        }
    }
}

__global__ __launch_bounds__(256) void k_fill(const int* __restrict__ ei, int* __restrict__ pos,
                                              int* __restrict__ elist) {
    int e = blockIdx.x * 256 + threadIdx.x;
    if (e >= NEDGES) return;
    int src = ei[e];
    int dst = ei[NEDGES + e];
    int p = atomicAdd(&pos[dst], 1);
    elist[p] = src;
}

// ---------------- gather-aggregate ----------------
__global__ __launch_bounds__(256) void k_agg(const short* __restrict__ xb,
                                             const int* __restrict__ rowptr,
                                             const int* __restrict__ elist,
                                             short* __restrict__ bufb) {
    int t = threadIdx.x;
    int w = t >> 6, lane = t & 63;
    int node = blockIdx.x * 4 + w;
    if (node >= NNODES) return;
    int beg = rowptr[node];
    int end = rowptr[node + 1];
    int deg = end - beg;
    int total = deg + 1;
    int sub = lane & 31, half = lane >> 5;
    const uint2* xr = (const uint2*)xb;

    float acc0 = 0.f, acc1 = 0.f, acc2 = 0.f, acc3 = 0.f;

    for (int base = 0; base < total; base += 64) {
        int j = base + lane;
        int ej = NNODES;  // zero row
        if (j < total) ej = (j == 0) ? node : elist[beg + j - 1];
        int cnt = min(64, total - base);
        int pairs = (cnt + 1) >> 1;
        for (int i = 0; i < pairs; i += 4) {
            int j0 = 2 * i + half;
            int r0 = __shfl(ej, j0);
            int r1 = __shfl(ej, j0 + 2);
            int r2 = __shfl(ej, j0 + 4);
            int r3 = __shfl(ej, j0 + 6);
            uint2 v0 = xr[(size_t)r0 * 32 + sub];
            uint2 v1 = xr[(size_t)r1 * 32 + sub];
            uint2 v2 = xr[(size_t)r2 * 32 + sub];
            uint2 v3 = xr[(size_t)r3 * 32 + sub];
            acc0 += b2f((short)(v0.x & 0xFFFF)) + b2f((short)(v1.x & 0xFFFF)) +
                    b2f((short)(v2.x & 0xFFFF)) + b2f((short)(v3.x & 0xFFFF));
            acc1 += b2f((short)(v0.x >> 16)) + b2f((short)(v1.x >> 16)) +
                    b2f((short)(v2.x >> 16)) + b2f((short)(v3.x >> 16));
            acc2 += b2f((short)(v0.y & 0xFFFF)) + b2f((short)(v1.y & 0xFFFF)) +
                    b2f((short)(v2.y & 0xFFFF)) + b2f((short)(v3.y & 0xFFFF));
            acc3 += b2f((short)(v0.y >> 16)) + b2f((short)(v1.y >> 16)) +
                    b2f((short)(v2.y >> 16)) + b2f((short)(v3.y >> 16));
        }
    }
    acc0 += __shfl_xor(acc0, 32);
    acc1 += __shfl_xor(acc1, 32);
    acc2 += __shfl_xor(acc2, 32);
    acc3 += __shfl_xor(acc3, 32);
    if (half == 0) {
        uint2 o;
        o.x = ((uint32_t)(unsigned short)f2b(acc1) << 16) | (uint32_t)(unsigned short)f2b(acc0);
        o.y = ((uint32_t)(unsigned short)f2b(acc3) << 16) | (uint32_t)(unsigned short)f2b(acc2);
        ((uint2*)bufb)[(size_t)node * 32 + sub] = o;
    }
}

// ---------------- stats: u = agg @ W1 (b1 cancels in BN); S,Q per column ----------
__global__ __launch_bounds__(256) void k_stats(const short* __restrict__ bufb,
                                               const short* __restrict__ W1pk,
                                               float* __restrict__ stats) {
    __shared__ float Sred[2][4][128];
    int t = threadIdx.x, w = t >> 6, l = t & 63;
    int r0 = blockIdx.x * 128;
    int row0 = (w & 1) * 64, col0 = (w >> 1) * 64;

    f32x4 acc[4][4];
#pragma unroll
    for (int r = 0; r < 4; ++r)
#pragma unroll
        for (int c = 0; c < 4; ++c) acc[r][c] = (f32x4){0.f, 0.f, 0.f, 0.f};

#pragma unroll
    for (int kb = 0; kb < 4; ++kb) {
        bf16x8 af[4], bw[4];
#pragma unroll
        for (int r = 0; r < 4; ++r)
            af[r] = *(const bf16x8*)(bufb + (size_t)(r0 + row0 + r * 16 + (l & 15)) * 128 +
                                     kb * 32 + (l >> 4) * 8);
#pragma unroll
        for (int c = 0; c < 4; ++c)
            bw[c] = *(const bf16x8*)(W1pk + ((((w >> 1) * 4 + c) * 4 + kb) * 64 + l) * 8);
#pragma unroll
        for (int r = 0; r < 4; ++r)
#pragma unroll
            for (int c = 0; c < 4; ++c) acc[r][c] = MFMA16(af[r], bw[c], acc[r][c]);
    }

    float s[4], q[4];
#pragma unroll
    for (int c = 0; c < 4; ++c) { s[c] = 0.f; q[c] = 0.f; }
#pragma unroll
    for (int c = 0; c < 4; ++c)
#pragma unroll
        for (int r = 0; r < 4; ++r)
#pragma unroll
            for (int rr = 0; rr < 4; ++rr) {
                int grow = r0 + row0 + r * 16 + (l >> 4) * 4 + rr;
                if (grow < NNODES) {
                    float v = acc[r][c][rr];
                    s[c] += v;
                    q[c] += v * v;
                }
            }
#pragma unroll
    for (int c = 0; c < 4; ++c) {
        s[c] += __shfl_xor(s[c], 16); s[c] += __shfl_xor(s[c], 32);
        q[c] += __shfl_xor(q[c], 16); q[c] += __shfl_xor(q[c], 32);
    }
    if (l < 16) {
#pragma unroll
        for (int c = 0; c < 4; ++c) {
            Sred[0][w][col0 + c * 16 + l] = s[c];
            Sred[1][w][col0 + c * 16 + l] = q[c];
        }
    }
    __syncthreads();
    if (t < 128) {
        int wb = (t < 64) ? 0 : 2;
        atomicAdd(stats + t, Sred[0][wb][t] + Sred[0][wb + 1][t]);
        atomicAdd(stats + 128 + t, Sred[1][wb][t] + Sred[1][wb + 1][t]);
    }
}

// ---------------- fused MLP, zero activation-LDS, 32 nodes/wave ----------------
// G1..G3 operand-swapped: C[c][node] = mfma(W^T as A, act as B); node stays in lane&15.
// TWO 16-node groups (A/B) share each weight fragment -> 2x weight reuse, 8 independent
// accumulator chains per ct-half (ILP). C -> next B via register pack + shuffles.
// G4 swaps back for coalesced stores.
__global__ __launch_bounds__(256, 3) void k_mlp(const short* __restrict__ bufb,
                                                const float* __restrict__ stats,
                                                const float* __restrict__ gamma,
                                                const float* __restrict__ beta,
                                                const short* __restrict__ Wt,
                                                const float* __restrict__ b2,
                                                const float* __restrict__ bm1,
                                                const float* __restrict__ bm2,
                                                float* __restrict__ out) {
    __shared__ float scl[3][128], shf[3][128], bm2s[64];

    int t = threadIdx.x, w = t >> 6, l = t & 63;
    int lr = l & 15, hi = l >> 4;
    size_t node0 = (size_t)blockIdx.x * 128 + w * 32;  // this wave's 32 nodes
    const short* Wm2pk = Wt + 49152;

    if (t < 128) {
        float mean = stats[t] * (1.0f / NNODES);
        float var = fmaxf(stats[128 + t] * (1.0f / NNODES) - mean * mean, 0.0f);
        float inv = rsqrtf(var + 1e-5f);
        float sc = gamma[t] * inv;
        scl[0][t] = sc;
        shf[0][t] = beta[t] - mean * sc;  // b1 cancels in batch-stats BN
        scl[1][t] = 1.0f;
        shf[1][t] = b2[t];
        scl[2][t] = 1.0f;
        shf[2][t] = bm1[t];
    }
    if (t < 64) bm2s[t] = bm2[t];
    __syncthreads();

    // B-frags straight from global: bv*[kt] = act[node][k=kt*32+hi*8+j]
    bf16x8 bvA[4], bvB[4];
#pragma unroll
    for (int kt = 0; kt < 4; ++kt) {
        bvA[kt] = *(const bf16x8*)(bufb + (node0 + lr) * 128 + kt * 32 + hi * 8);
        bvB[kt] = *(const bf16x8*)(bufb + (node0 + 16 + lr) * 128 + kt * 32 + hi * 8);
    }

    unsigned pwA[8][2], pwB[8][2];  // packed C: pw[ct][w2] = ch ct*16+hi*4+2*w2+{0,1}

    // ---- G1..G3: swapped GEMM, epilogue v = relu(a*scl[g]+shf[g]) ----
    for (int g = 0; g < 3; ++g) {
        const short* Wg = Wt + g * 16384;
#pragma unroll
        for (int ch = 0; ch < 2; ++ch) {
            f32x4 aA[4], aB[4];
#pragma unroll
            for (int cc = 0; cc < 4; ++cc) {
                aA[cc] = (f32x4){0.f, 0.f, 0.f, 0.f};
                aB[cc] = (f32x4){0.f, 0.f, 0.f, 0.f};
            }
#pragma unroll
            for (int kt = 0; kt < 4; ++kt) {
                bf16x8 wv[4];
#pragma unroll
                for (int cc = 0; cc < 4; ++cc)
                    wv[cc] = *(const bf16x8*)(Wg + ((((ch * 4 + cc) * 4) + kt) * 64 + l) * 8);
#pragma unroll
                for (int cc = 0; cc < 4; ++cc) {
                    aA[cc] = MFMA16(wv[cc], bvA[kt], aA[cc]);
                    aB[cc] = MFMA16(wv[cc], bvB[kt], aB[cc]);
                }
            }
#pragma unroll
            for (int cc = 0; cc < 4; ++cc) {
                int ct = ch * 4 + cc;
                int c0 = ct * 16 + hi * 4;
                float4 s4 = *(const float4*)&scl[g][c0];
                float4 h4 = *(const float4*)&shf[g][c0];
                pwA[ct][0] = packbf(fmaxf(aA[cc][0] * s4.x + h4.x, 0.f),
                                    fmaxf(aA[cc][1] * s4.y + h4.y, 0.f));
                pwA[ct][1] = packbf(fmaxf(aA[cc][2] * s4.z + h4.z, 0.f),
                                    fmaxf(aA[cc][3] * s4.w + h4.w, 0.f));
                pwB[ct][0] = packbf(fmaxf(aB[cc][0] * s4.x + h4.x, 0.f),
                                    fmaxf(aB[cc][1] * s4.y + h4.y, 0.f));
                pwB[ct][1] = packbf(fmaxf(aB[cc][2] * s4.z + h4.z, 0.f),
                                    fmaxf(aB[cc][3] * s4.w + h4.w, 0.f));
            }
        }
        // redistribute pw -> bv: elem j of bv[kt] = channel kt*32+hi*8+j, node lr.
        // src: ct_src = 2kt + h2_dest, lane (2*h1_dest + (jp>>1))*16 + lr, word jp&1.
        // Shuffle both ct candidates (lane-uniform), select with dest h2 after the pull.
        {
            int h2 = hi >> 1, h1 = hi & 1;
#pragma unroll
            for (int kt = 0; kt < 4; ++kt) {
                unsigned nwA[4], nwB[4];
#pragma unroll
                for (int jp = 0; jp < 4; ++jp) {
                    int srcl = (2 * h1 + (jp >> 1)) * 16 + lr;
                    unsigned veA = (unsigned)__shfl((int)pwA[2 * kt][jp & 1], srcl);
                    unsigned voA = (unsigned)__shfl((int)pwA[2 * kt + 1][jp & 1], srcl);
                    unsigned veB = (unsigned)__shfl((int)pwB[2 * kt][jp & 1], srcl);
                    unsigned voB = (unsigned)__shfl((int)pwB[2 * kt + 1][jp & 1], srcl);
                    nwA[jp] = h2 ? voA : veA;
                    nwB[jp] = h2 ? voB : veB;
                }
                u32x4 uqA = (u32x4){nwA[0], nwA[1], nwA[2], nwA[3]};
                u32x4 uqB = (u32x4){nwB[0], nwB[1], nwB[2], nwB[3]};
                bvA[kt] = __builtin_bit_cast(bf16x8, uqA);
                bvB[kt] = __builtin_bit_cast(bf16x8, uqB);
            }
        }
    }

    // ---- G4: h @ Wm2 + bm2 -> out (bv as A-frags: same lane layout) ----
#pragma unroll
    for (int ct = 0; ct < 4; ++ct) {
        f32x4 aA = (f32x4){0.f, 0.f, 0.f, 0.f};
        f32x4 aB = (f32x4){0.f, 0.f, 0.f, 0.f};
#pragma unroll
        for (int kt = 0; kt < 4; ++kt) {
            bf16x8 wv = *(const bf16x8*)(Wm2pk + ((ct * 4 + kt) * 64 + l) * 8);
            aA = MFMA16(bvA[kt], wv, aA);
            aB = MFMA16(bvB[kt], wv, aB);
        }
        float bias = bm2s[ct * 16 + lr];
#pragma unroll
        for (int rr = 0; rr < 4; ++rr) {
            size_t growA = node0 + hi * 4 + rr;
            size_t growB = node0 + 16 + hi * 4 + rr;
            if (growA < NNODES) out[growA * 64 + ct * 16 + lr] = aA[rr] + bias;
            if (growB < NNODES) out[growB * 64 + ct * 16 + lr] = aB[rr] + bias;
        }
    }
}

// ---------------- launch ----------------
extern "C" void kernel_launch(void* const* d_in, const int* in_sizes, int n_in,
                              void* d_out, int out_size, void* d_ws, size_t ws_size,
                              hipStream_t stream) {
    const float* x     = (const float*)d_in[0];
    const int*   ei    = (const int*)d_in[1];
    const float* W1    = (const float*)d_in[2];
    const float* gamma = (const float*)d_in[4];
    const float* beta  = (const float*)d_in[5];
    const float* W2    = (const float*)d_in[6];
    const float* b2    = (const float*)d_in[7];
    const float* Wm1   = (const float*)d_in[8];
    const float* bm1   = (const float*)d_in[9];
    const float* Wm2   = (const float*)d_in[10];
    const float* bm2   = (const float*)d_in[11];
    float* out = (float*)d_out;

    char* ws = (char*)d_ws;
    short* xb    = (short*)ws;                           // (N+1)*128 bf16 (last row zeros)
    short* bufb  = xb + (size_t)(NNODES + 1) * 128;      // (N+128)*128 bf16 (tail padding)
    short* Wt    = bufb + (size_t)(NNODES + 128) * 128;  // 57344 bf16 packed fragments
    float* stats = (float*)(Wt + 57344);                 // 256 f32
    int* rowptr  = (int*)(stats + 256);                  // N+1
    int* pos     = rowptr + (NNODES + 1);                // N
    int* elist   = pos + NNODES;                         // E
    int* bsums   = elist + NEDGES;                       // 128

    int gE = (NEDGES + 255) / 256;
    int gPrep = ((NNODES + 1) * 16 + 255) / 256;

    k_prep<<<gPrep, 256, 0, stream>>>(x, W1, W2, Wm1, Wm2, xb, Wt, pos, stats);
    k_hist<<<gE, 256, 0, stream>>>(ei, pos);
    k_scan1<<<SCAN_NB, 256, 0, stream>>>(pos, bsums);
    k_scan2<<<1, 64, 0, stream>>>(bsums, rowptr);
    k_scan3<<<SCAN_NB, 256, 0, stream>>>(pos, bsums, rowptr, pos);
    k_fill<<<gE, 256, 0, stream>>>(ei, pos, elist);
    k_agg<<<(NNODES + 3) / 4, 256, 0, stream>>>(xb, rowptr, elist, bufb);

    int nblkS = (NNODES + 127) / 128;
    k_stats<<<nblkS, 256, 0, stream>>>(bufb, Wt, stats);
    int nblkM = (NNODES + 127) / 128;
    k_mlp<<<nblkM, 256, 0, stream>>>(bufb, stats, gamma, beta, Wt, b2, bm1, bm2, out);
}

// Round 11
// 172.083 us; speedup vs baseline: 2.5296x; 1.0023x over previous
//
#include <hip/hip_runtime.h>
#include <hip/hip_bf16.h>
#include <stdint.h>

#define NNODES 100000
#define NEDGES 600000
#define SCAN_CHUNK 1024
#define SCAN_NB 98  // ceil(100000/1024)

typedef __attribute__((ext_vector_type(8))) short bf16x8;
typedef __attribute__((ext_vector_type(4))) float f32x4;
typedef __attribute__((ext_vector_type(4))) unsigned int u32x4;

__device__ inline float b2f(short b) {
    union { unsigned u; float f; } v;
    v.u = ((unsigned)(unsigned short)b) << 16;
    return v.f;
}
__device__ inline short f2b(float f) {
    union { float f; unsigned u; } v;
    v.f = f;
    unsigned r = (v.u + 0x7FFFu + ((v.u >> 16) & 1u)) >> 16;
    return (short)r;
}
__device__ inline unsigned packbf(float lo, float hi) {
    return ((unsigned)(unsigned short)f2b(hi) << 16) | (unsigned)(unsigned short)f2b(lo);
}
#define MFMA16(a, b, c) __builtin_amdgcn_mfma_f32_16x16x32_bf16(a, b, c, 0, 0, 0)

// async global->LDS linear copy: n iters of 4KB (256 threads x 16B).
// LDS dest is wave-uniform base + lane*16 (HW); global src is per-lane.
__device__ inline void stage_lds(const short* __restrict__ g, short* s, int w, int l, int n) {
#pragma unroll
    for (int i = 0; i < n; ++i) {
        int base = i * 4096 + w * 1024;
        __builtin_amdgcn_global_load_lds(
            (const __attribute__((address_space(1))) void*)((const char*)g + base + l * 16),
            (__attribute__((address_space(3))) void*)((char*)s + base), 16, 0, 0);
    }
}

// ---------------- fused prep ----------------
// zero pos/stats; x->bf16 (+zero row); weights -> bf16 packed per-fragment, ct-major:
// Wpk[ct][kt][lane][j] = W[k = kt*32 + (lane>>4)*8 + j][c = ct*16 + (lane&15)]
__global__ __launch_bounds__(256) void k_prep(const float* __restrict__ x,
                                              const float* __restrict__ W1,
                                              const float* __restrict__ W2,
                                              const float* __restrict__ Wm1,
                                              const float* __restrict__ Wm2,
                                              short* __restrict__ xb, short* __restrict__ Wt,
                                              int* __restrict__ pos, float* __restrict__ stats) {
    int i = blockIdx.x * 256 + threadIdx.x;
    if (i < (NNODES + 1) * 16) {
        bf16x8 o = (bf16x8){0, 0, 0, 0, 0, 0, 0, 0};
        if (i < NNODES * 16) {
            const float4* p = (const float4*)(x + (size_t)i * 8);
            float4 a = p[0], b = p[1];
            o[0] = f2b(a.x); o[1] = f2b(a.y); o[2] = f2b(a.z); o[3] = f2b(a.w);
            o[4] = f2b(b.x); o[5] = f2b(b.y); o[6] = f2b(b.z); o[7] = f2b(b.w);
        }
        *(bf16x8*)(xb + (size_t)i * 8) = o;
    }
    if (i < NNODES) pos[i] = 0;
    if (i < 57344) {
        int jj, lane, kt, ct;
        const float* W;
        int ldw, off;
        if (i < 16384) { off = i; W = W1; ldw = 128; }
        else if (i < 32768) { off = i - 16384; W = W2; ldw = 128; }
        else if (i < 49152) { off = i - 32768; W = Wm1; ldw = 128; }
        else { off = i - 49152; W = Wm2; ldw = 64; }
        jj = off & 7;
        lane = (off >> 3) & 63;
        kt = (off >> 9) & 3;
        ct = (off >> 11) & 7;  // for Wm2 only 0..3 occur (off < 8192)
        int lr = lane & 15, hi = lane >> 4;
        int c = ct * 16 + lr;
        int k = kt * 32 + hi * 8 + jj;
        Wt[i] = f2b(W[k * ldw + c]);
    }
    if (i < 256) stats[i] = 0.0f;
}

// ---------------- CSR build ----------------

__global__ __launch_bounds__(256) void k_hist(const int* __restrict__ ei, int* __restrict__ cnt) {
    int e = blockIdx.x * 256 + threadIdx.x;
    if (e < NEDGES) atomicAdd(&cnt[ei[NEDGES + e]], 1);
}

// per-block sums of 1024 counts
__global__ __launch_bounds__(256) void k_scan1(const int* __restrict__ cnt, int* __restrict__ bsums) {
    __shared__ int sd[256];
    int b = blockIdx.x, t = threadIdx.x;
    int base = b * SCAN_CHUNK + t * 4;
    int s = 0;
#pragma unroll
    for (int i = 0; i < 4; ++i) {
        int idx = base + i;
        if (idx < NNODES) s += cnt[idx];
    }
    sd[t] = s;
    __syncthreads();
    for (int off = 128; off > 0; off >>= 1) {
        if (t < off) sd[t] += sd[t + off];
        __syncthreads();
    }
    if (t == 0) bsums[b] = sd[0];
}

// serial scan of 98 block sums (tiny)
__global__ __launch_bounds__(64) void k_scan2(int* __restrict__ bsums, int* __restrict__ rowptr) {
    if (threadIdx.x == 0 && blockIdx.x == 0) {
        int run = 0;
        for (int b = 0; b < SCAN_NB; ++b) {
            int v = bsums[b];
            bsums[b] = run;
            run += v;
        }
        rowptr[NNODES] = run;
    }
}

// full exclusive scan: rowptr[i] and pos[i] (fill cursor). cnt and pos may alias.
__global__ __launch_bounds__(256) void k_scan3(const int* __restrict__ cnt,
                                               const int* __restrict__ bsums,
                                               int* __restrict__ rowptr, int* __restrict__ pos) {
    __shared__ int sd[256];
    int b = blockIdx.x, t = threadIdx.x;
    int base = b * SCAN_CHUNK + t * 4;
    int v[4];
    int s = 0;
#pragma unroll
    for (int i = 0; i < 4; ++i) {
        int idx = base + i;
        v[i] = (idx < NNODES) ? cnt[idx] : 0;
        s += v[i];
    }
    sd[t] = s;
    __syncthreads();
    for (int off = 1; off < 256; off <<= 1) {
        int val = (t >= off) ? sd[t - off] : 0;
        __syncthreads();
        sd[t] += val;
        __syncthreads();
    }
    int run = sd[t] - s + bsums[b];
#pragma unroll
    for (int i = 0; i < 4; ++i) {
        int idx = base + i;
        if (idx < NNODES) {
            rowptr[idx] = run;
            pos[idx] = run;
            run += v[i];
        }
    }
}

__global__ __launch_bounds__(256) void k_fill(const int* __restrict__ ei, int* __restrict__ pos,
                                              int* __restrict__ elist) {
    int e = blockIdx.x * 256 + threadIdx.x;
    if (e >= NEDGES) return;
    int src = ei[e];
    int dst = ei[NEDGES + e];
    int p = atomicAdd(&pos[dst], 1);
    elist[p] = src;
}

// ---------------- gather-aggregate ----------------
__global__ __launch_bounds__(256) void k_agg(const short* __restrict__ xb,
                                             const int* __restrict__ rowptr,
                                             const int* __restrict__ elist,
                                             short* __restrict__ bufb) {
    int t = threadIdx.x;
    int w = t >> 6, lane = t & 63;
    int node = blockIdx.x * 4 + w;
    if (node >= NNODES) return;
    int beg = rowptr[node];
    int end = rowptr[node + 1];
    int deg = end - beg;
    int total = deg + 1;
    int sub = lane & 31, half = lane >> 5;
    const uint2* xr = (const uint2*)xb;

    float acc0 = 0.f, acc1 = 0.f, acc2 = 0.f, acc3 = 0.f;

    for (int base = 0; base < total; base += 64) {
        int j = base + lane;
        int ej = NNODES;  // zero row
        if (j < total) ej = (j == 0) ? node : elist[beg + j - 1];
        int cnt = min(64, total - base);
        int pairs = (cnt + 1) >> 1;
        for (int i = 0; i < pairs; i += 4) {
            int j0 = 2 * i + half;
            int r0 = __shfl(ej, j0);
            int r1 = __shfl(ej, j0 + 2);
            int r2 = __shfl(ej, j0 + 4);
            int r3 = __shfl(ej, j0 + 6);
            uint2 v0 = xr[(size_t)r0 * 32 + sub];
            uint2 v1 = xr[(size_t)r1 * 32 + sub];
            uint2 v2 = xr[(size_t)r2 * 32 + sub];
            uint2 v3 = xr[(size_t)r3 * 32 + sub];
            acc0 += b2f((short)(v0.x & 0xFFFF)) + b2f((short)(v1.x & 0xFFFF)) +
                    b2f((short)(v2.x & 0xFFFF)) + b2f((short)(v3.x & 0xFFFF));
            acc1 += b2f((short)(v0.x >> 16)) + b2f((short)(v1.x >> 16)) +
                    b2f((short)(v2.x >> 16)) + b2f((short)(v3.x >> 16));
            acc2 += b2f((short)(v0.y & 0xFFFF)) + b2f((short)(v1.y & 0xFFFF)) +
                    b2f((short)(v2.y & 0xFFFF)) + b2f((short)(v3.y & 0xFFFF));
            acc3 += b2f((short)(v0.y >> 16)) + b2f((short)(v1.y >> 16)) +
                    b2f((short)(v2.y >> 16)) + b2f((short)(v3.y >> 16));
        }
    }
    acc0 += __shfl_xor(acc0, 32);
    acc1 += __shfl_xor(acc1, 32);
    acc2 += __shfl_xor(acc2, 32);
    acc3 += __shfl_xor(acc3, 32);
    if (half == 0) {
        uint2 o;
        o.x = ((uint32_t)(unsigned short)f2b(acc1) << 16) | (uint32_t)(unsigned short)f2b(acc0);
        o.y = ((uint32_t)(unsigned short)f2b(acc3) << 16) | (uint32_t)(unsigned short)f2b(acc2);
        ((uint2*)bufb)[(size_t)node * 32 + sub] = o;
    }
}

// ---------------- stats: u = agg @ W1 (b1 cancels in BN); S,Q per column ----------
__global__ __launch_bounds__(256) void k_stats(const short* __restrict__ bufb,
                                               const short* __restrict__ W1pk,
                                               float* __restrict__ stats) {
    __shared__ float Sred[2][4][128];
    int t = threadIdx.x, w = t >> 6, l = t & 63;
    int r0 = blockIdx.x * 128;
    int row0 = (w & 1) * 64, col0 = (w >> 1) * 64;

    f32x4 acc[4][4];
#pragma unroll
    for (int r = 0; r < 4; ++r)
#pragma unroll
        for (int c = 0; c < 4; ++c) acc[r][c] = (f32x4){0.f, 0.f, 0.f, 0.f};

#pragma unroll
    for (int kb = 0; kb < 4; ++kb) {
        bf16x8 af[4], bw[4];
#pragma unroll
        for (int r = 0; r < 4; ++r)
            af[r] = *(const bf16x8*)(bufb + (size_t)(r0 + row0 + r * 16 + (l & 15)) * 128 +
                                     kb * 32 + (l >> 4) * 8);
#pragma unroll
        for (int c = 0; c < 4; ++c)
            bw[c] = *(const bf16x8*)(W1pk + ((((w >> 1) * 4 + c) * 4 + kb) * 64 + l) * 8);
#pragma unroll
        for (int r = 0; r < 4; ++r)
#pragma unroll
            for (int c = 0; c < 4; ++c) acc[r][c] = MFMA16(af[r], bw[c], acc[r][c]);
    }

    float s[4], q[4];
#pragma unroll
    for (int c = 0; c < 4; ++c) { s[c] = 0.f; q[c] = 0.f; }
#pragma unroll
    for (int c = 0; c < 4; ++c)
#pragma unroll
        for (int r = 0; r < 4; ++r)
#pragma unroll
            for (int rr = 0; rr < 4; ++rr) {
                int grow = r0 + row0 + r * 16 + (l >> 4) * 4 + rr;
                if (grow < NNODES) {
                    float v = acc[r][c][rr];
                    s[c] += v;
                    q[c] += v * v;
                }
            }
#pragma unroll
    for (int c = 0; c < 4; ++c) {
        s[c] += __shfl_xor(s[c], 16); s[c] += __shfl_xor(s[c], 32);
        q[c] += __shfl_xor(q[c], 16); q[c] += __shfl_xor(q[c], 32);
    }
    if (l < 16) {
#pragma unroll
        for (int c = 0; c < 4; ++c) {
            Sred[0][w][col0 + c * 16 + l] = s[c];
            Sred[1][w][col0 + c * 16 + l] = q[c];
        }
    }
    __syncthreads();
    if (t < 128) {
        int wb = (t < 64) ? 0 : 2;
        atomicAdd(stats + t, Sred[0][wb][t] + Sred[0][wb + 1][t]);
        atomicAdd(stats + 128 + t, Sred[1][wb][t] + Sred[1][wb + 1][t]);
    }
}

// ---------------- fused MLP, 32 nodes/wave, LDS-staged weights ----------------
// Weights staged once per block (4 waves share) into a 32KB LDS buffer via
// global_load_lds; fragments then read from LDS (16B stride = 2-way aliasing, free).
// G1..G3 operand-swapped: C[c][node] = mfma(W^T as A, act as B); node stays in lane&15.
// C -> next B via register pack + shuffles. G4 swaps back for coalesced stores.
__global__ __launch_bounds__(256, 4) void k_mlp(const short* __restrict__ bufb,
                                                const float* __restrict__ stats,
                                                const float* __restrict__ gamma,
                                                const float* __restrict__ beta,
                                                const short* __restrict__ Wt,
                                                const float* __restrict__ b2,
                                                const float* __restrict__ bm1,
                                                const float* __restrict__ bm2,
                                                float* __restrict__ out) {
    __shared__ __align__(16) short wbuf[16384];  // 32KB weight stage
    __shared__ float scl[3][128], shf[3][128], bm2s[64];

    int t = threadIdx.x, w = t >> 6, l = t & 63;
    int lr = l & 15, hi = l >> 4;
    size_t node0 = (size_t)blockIdx.x * 128 + w * 32;  // this wave's 32 nodes

    // stage W1 (32KB) + tables
    stage_lds(Wt, wbuf, w, l, 8);
    if (t < 128) {
        float mean = stats[t] * (1.0f / NNODES);
        float var = fmaxf(stats[128 + t] * (1.0f / NNODES) - mean * mean, 0.0f);
        float inv = rsqrtf(var + 1e-5f);
        float sc = gamma[t] * inv;
        scl[0][t] = sc;
        shf[0][t] = beta[t] - mean * sc;  // b1 cancels in batch-stats BN
        scl[1][t] = 1.0f;
        shf[1][t] = b2[t];
        scl[2][t] = 1.0f;
        shf[2][t] = bm1[t];
    }
    if (t < 64) bm2s[t] = bm2[t];

    // B-frags straight from global: bv*[kt] = act[node][k=kt*32+hi*8+j]
    bf16x8 bvA[4], bvB[4];
#pragma unroll
    for (int kt = 0; kt < 4; ++kt) {
        bvA[kt] = *(const bf16x8*)(bufb + (node0 + lr) * 128 + kt * 32 + hi * 8);
        bvB[kt] = *(const bf16x8*)(bufb + (node0 + 16 + lr) * 128 + kt * 32 + hi * 8);
    }
    __syncthreads();  // W1 + tables ready

    unsigned pwA[8][2], pwB[8][2];  // packed C: pw[ct][w2] = ch ct*16+hi*4+2*w2+{0,1}

    // ---- G1..G3: swapped GEMM, epilogue v = relu(a*scl[g]+shf[g]) ----
    for (int g = 0; g < 3; ++g) {
#pragma unroll
        for (int ch = 0; ch < 2; ++ch) {
            f32x4 aA[4], aB[4];
#pragma unroll
            for (int cc = 0; cc < 4; ++cc) {
                aA[cc] = (f32x4){0.f, 0.f, 0.f, 0.f};
                aB[cc] = (f32x4){0.f, 0.f, 0.f, 0.f};
            }
#pragma unroll
            for (int kt = 0; kt < 4; ++kt) {
                bf16x8 wv[4];
#pragma unroll
                for (int cc = 0; cc < 4; ++cc)
                    wv[cc] = *(const bf16x8*)(wbuf + ((((ch * 4 + cc) * 4) + kt) * 64 + l) * 8);
#pragma unroll
                for (int cc = 0; cc < 4; ++cc) {
                    aA[cc] = MFMA16(wv[cc], bvA[kt], aA[cc]);
                    aB[cc] = MFMA16(wv[cc], bvB[kt], aB[cc]);
                }
            }
#pragma unroll
            for (int cc = 0; cc < 4; ++cc) {
                int ct = ch * 4 + cc;
                int c0 = ct * 16 + hi * 4;
                float4 s4 = *(const float4*)&scl[g][c0];
                float4 h4 = *(const float4*)&shf[g][c0];
                pwA[ct][0] = packbf(fmaxf(aA[cc][0] * s4.x + h4.x, 0.f),
                                    fmaxf(aA[cc][1] * s4.y + h4.y, 0.f));
                pwA[ct][1] = packbf(fmaxf(aA[cc][2] * s4.z + h4.z, 0.f),
                                    fmaxf(aA[cc][3] * s4.w + h4.w, 0.f));
                pwB[ct][0] = packbf(fmaxf(aB[cc][0] * s4.x + h4.x, 0.f),
                                    fmaxf(aB[cc][1] * s4.y + h4.y, 0.f));
                pwB[ct][1] = packbf(fmaxf(aB[cc][2] * s4.z + h4.z, 0.f),
                                    fmaxf(aB[cc][3] * s4.w + h4.w, 0.f));
            }
        }
        __syncthreads();  // all waves done reading wbuf for this g
        if (g < 2) stage_lds(Wt + (g + 1) * 16384, wbuf, w, l, 8);
        else       stage_lds(Wt + 49152, wbuf, w, l, 4);  // Wm2, 16KB

        // redistribute pw -> bv: elem j of bv[kt] = channel kt*32+hi*8+j, node lr.
        // src: ct_src = 2kt + h2_dest, lane (2*h1_dest + (jp>>1))*16 + lr, word jp&1.
        // Shuffle both ct candidates (lane-uniform), select with dest h2 after the pull.
        {
            int h2 = hi >> 1, h1 = hi & 1;
#pragma unroll
            for (int kt = 0; kt < 4; ++kt) {
                unsigned nwA[4], nwB[4];
#pragma unroll
                for (int jp = 0; jp < 4; ++jp) {
                    int srcl = (2 * h1 + (jp >> 1)) * 16 + lr;
                    unsigned veA = (unsigned)__shfl((int)pwA[2 * kt][jp & 1], srcl);
                    unsigned voA = (unsigned)__shfl((int)pwA[2 * kt + 1][jp & 1], srcl);
                    unsigned veB = (unsigned)__shfl((int)pwB[2 * kt][jp & 1], srcl);
                    unsigned voB = (unsigned)__shfl((int)pwB[2 * kt + 1][jp & 1], srcl);
                    nwA[jp] = h2 ? voA : veA;
                    nwB[jp] = h2 ? voB : veB;
                }
                u32x4 uqA = (u32x4){nwA[0], nwA[1], nwA[2], nwA[3]};
                u32x4 uqB = (u32x4){nwB[0], nwB[1], nwB[2], nwB[3]};
                bvA[kt] = __builtin_bit_cast(bf16x8, uqA);
                bvB[kt] = __builtin_bit_cast(bf16x8, uqB);
            }
        }
        __syncthreads();  // next weights staged (vmcnt drained by barrier)
    }

    // ---- G4: h @ Wm2 + bm2 -> out (bv as A-frags: same lane layout) ----
#pragma unroll
    for (int ct = 0; ct < 4; ++ct) {
        f32x4 aA = (f32x4){0.f, 0.f, 0.f, 0.f};
        f32x4 aB = (f32x4){0.f, 0.f, 0.f, 0.f};
#pragma unroll
        for (int kt = 0; kt < 4; ++kt) {
            bf16x8 wv = *(const bf16x8*)(wbuf + ((ct * 4 + kt) * 64 + l) * 8);
            aA = MFMA16(bvA[kt], wv, aA);
            aB = MFMA16(bvB[kt], wv, aB);
        }
        float bias = bm2s[ct * 16 + lr];
#pragma unroll
        for (int rr = 0; rr < 4; ++rr) {
            size_t growA = node0 + hi * 4 + rr;
            size_t growB = node0 + 16 + hi * 4 + rr;
            if (growA < NNODES) out[growA * 64 + ct * 16 + lr] = aA[rr] + bias;
            if (growB < NNODES) out[growB * 64 + ct * 16 + lr] = aB[rr] + bias;
        }
    }
}

// ---------------- launch ----------------
extern "C" void kernel_launch(void* const* d_in, const int* in_sizes, int n_in,
                              void* d_out, int out_size, void* d_ws, size_t ws_size,
                              hipStream_t stream) {
    const float* x     = (const float*)d_in[0];
    const int*   ei    = (const int*)d_in[1];
    const float* W1    = (const float*)d_in[2];
    const float* gamma = (const float*)d_in[4];
    const float* beta  = (const float*)d_in[5];
    const float* W2    = (const float*)d_in[6];
    const float* b2    = (const float*)d_in[7];
    const float* Wm1   = (const float*)d_in[8];
    const float* bm1   = (const float*)d_in[9];
    const float* Wm2   = (const float*)d_in[10];
    const float* bm2   = (const float*)d_in[11];
    float* out = (float*)d_out;

    char* ws = (char*)d_ws;
    short* xb    = (short*)ws;                           // (N+1)*128 bf16 (last row zeros)
    short* bufb  = xb + (size_t)(NNODES + 1) * 128;      // (N+128)*128 bf16 (tail padding)
    short* Wt    = bufb + (size_t)(NNODES + 128) * 128;  // 57344 bf16 packed fragments
    float* stats = (float*)(Wt + 57344);                 // 256 f32
    int* rowptr  = (int*)(stats + 256);                  // N+1
    int* pos     = rowptr + (NNODES + 1);                // N
    int* elist   = pos + NNODES;                         // E
    int* bsums   = elist + NEDGES;                       // 128

    int gE = (NEDGES + 255) / 256;
    int gPrep = ((NNODES + 1) * 16 + 255) / 256;

    k_prep<<<gPrep, 256, 0, stream>>>(x, W1, W2, Wm1, Wm2, xb, Wt, pos, stats);
    k_hist<<<gE, 256, 0, stream>>>(ei, pos);
    k_scan1<<<SCAN_NB, 256, 0, stream>>>(pos, bsums);
    k_scan2<<<1, 64, 0, stream>>>(bsums, rowptr);
    k_scan3<<<SCAN_NB, 256, 0, stream>>>(pos, bsums, rowptr, pos);
    k_fill<<<gE, 256, 0, stream>>>(ei, pos, elist);
    k_agg<<<(NNODES + 3) / 4, 256, 0, stream>>>(xb, rowptr, elist, bufb);

    int nblkS = (NNODES + 127) / 128;
    k_stats<<<nblkS, 256, 0, stream>>>(bufb, Wt, stats);
    int nblkM = (NNODES + 127) / 128;
    k_mlp<<<nblkM, 256, 0, stream>>>(bufb, stats, gamma, beta, Wt, b2, bm1, bm2, out);
}

// Round 12
// 167.700 us; speedup vs baseline: 2.5957x; 1.0261x over previous
//
#include <hip/hip_runtime.h>
#include <hip/hip_bf16.h>
#include <stdint.h>

#define NNODES 100000
#define NEDGES 600000
#define SCAN_CHUNK 1024
#define SCAN_NB 98  // ceil(100000/1024)

typedef __attribute__((ext_vector_type(8))) short bf16x8;
typedef __attribute__((ext_vector_type(4))) float f32x4;
typedef __attribute__((ext_vector_type(4))) unsigned int u32x4;

__device__ inline float b2f(short b) {
    union { unsigned u; float f; } v;
    v.u = ((unsigned)(unsigned short)b) << 16;
    return v.f;
}
__device__ inline short f2b(float f) {
    union { float f; unsigned u; } v;
    v.f = f;
    unsigned r = (v.u + 0x7FFFu + ((v.u >> 16) & 1u)) >> 16;
    return (short)r;
}
__device__ inline unsigned packbf(float lo, float hi) {
    return ((unsigned)(unsigned short)f2b(hi) << 16) | (unsigned)(unsigned short)f2b(lo);
}
// LDS XOR swizzle for row-major [row][256B] bf16 tiles (16B granularity)
__device__ inline int swz(int row, int kbyte) {
    return (row * 256 + kbyte) ^ ((row & 7) << 4);
}
#define MFMA16(a, b, c) __builtin_amdgcn_mfma_f32_16x16x32_bf16(a, b, c, 0, 0, 0)

// async global->LDS linear copy: n iters of 4KB (256 threads x 16B).
__device__ inline void stage_lds(const short* __restrict__ g, short* s, int w, int l, int n) {
#pragma unroll
    for (int i = 0; i < n; ++i) {
        int base = i * 4096 + w * 1024;
        __builtin_amdgcn_global_load_lds(
            (const __attribute__((address_space(1))) void*)((const char*)g + base + l * 16),
            (__attribute__((address_space(3))) void*)((char*)s + base), 16, 0, 0);
    }
}

// ---------------- fused prep ----------------
// zero pos/stats; x->bf16 (+zero row); weights -> bf16 packed per-fragment, ct-major:
// Wpk[ct][kt][lane][j] = W[k = kt*32 + (lane>>4)*8 + j][c = ct*16 + (lane&15)]
__global__ __launch_bounds__(256) void k_prep(const float* __restrict__ x,
                                              const float* __restrict__ W1,
                                              const float* __restrict__ W2,
                                              const float* __restrict__ Wm1,
                                              const float* __restrict__ Wm2,
                                              short* __restrict__ xb, short* __restrict__ Wt,
                                              int* __restrict__ pos, float* __restrict__ stats) {
    int i = blockIdx.x * 256 + threadIdx.x;
    if (i < (NNODES + 1) * 16) {
        bf16x8 o = (bf16x8){0, 0, 0, 0, 0, 0, 0, 0};
        if (i < NNODES * 16) {
            const float4* p = (const float4*)(x + (size_t)i * 8);
            float4 a = p[0], b = p[1];
            o[0] = f2b(a.x); o[1] = f2b(a.y); o[2] = f2b(a.z); o[3] = f2b(a.w);
            o[4] = f2b(b.x); o[5] = f2b(b.y); o[6] = f2b(b.z); o[7] = f2b(b.w);
        }
        *(bf16x8*)(xb + (size_t)i * 8) = o;
    }
    if (i < NNODES) pos[i] = 0;
    if (i < 57344) {
        int jj, lane, kt, ct;
        const float* W;
        int ldw, off;
        if (i < 16384) { off = i; W = W1; ldw = 128; }
        else if (i < 32768) { off = i - 16384; W = W2; ldw = 128; }
        else if (i < 49152) { off = i - 32768; W = Wm1; ldw = 128; }
        else { off = i - 49152; W = Wm2; ldw = 64; }
        jj = off & 7;
        lane = (off >> 3) & 63;
        kt = (off >> 9) & 3;
        ct = (off >> 11) & 7;  // for Wm2 only 0..3 occur (off < 8192)
        int lr = lane & 15, hi = lane >> 4;
        int c = ct * 16 + lr;
        int k = kt * 32 + hi * 8 + jj;
        Wt[i] = f2b(W[k * ldw + c]);
    }
    if (i < 256) stats[i] = 0.0f;
}

// ---------------- CSR build ----------------

__global__ __launch_bounds__(256) void k_hist(const int* __restrict__ ei, int* __restrict__ cnt) {
    int e = blockIdx.x * 256 + threadIdx.x;
    if (e < NEDGES) atomicAdd(&cnt[ei[NEDGES + e]], 1);
}

// per-block sums of 1024 counts
__global__ __launch_bounds__(256) void k_scan1(const int* __restrict__ cnt, int* __restrict__ bsums) {
    __shared__ int sd[256];
    int b = blockIdx.x, t = threadIdx.x;
    int base = b * SCAN_CHUNK + t * 4;
    int s = 0;
#pragma unroll
    for (int i = 0; i < 4; ++i) {
        int idx = base + i;
        if (idx < NNODES) s += cnt[idx];
    }
    sd[t] = s;
    __syncthreads();
    for (int off = 128; off > 0; off >>= 1) {
        if (t < off) sd[t] += sd[t + off];
        __syncthreads();
    }
    if (t == 0) bsums[b] = sd[0];
}

// serial scan of 98 block sums (tiny)
__global__ __launch_bounds__(64) void k_scan2(int* __restrict__ bsums, int* __restrict__ rowptr) {
    if (threadIdx.x == 0 && blockIdx.x == 0) {
        int run = 0;
        for (int b = 0; b < SCAN_NB; ++b) {
            int v = bsums[b];
            bsums[b] = run;
            run += v;
        }
        rowptr[NNODES] = run;
    }
}

// full exclusive scan: rowptr[i] and pos[i] (fill cursor). cnt and pos may alias.
__global__ __launch_bounds__(256) void k_scan3(const int* __restrict__ cnt,
                                               const int* __restrict__ bsums,
                                               int* __restrict__ rowptr, int* __restrict__ pos) {
    __shared__ int sd[256];
    int b = blockIdx.x, t = threadIdx.x;
    int base = b * SCAN_CHUNK + t * 4;
    int v[4];
    int s = 0;
#pragma unroll
    for (int i = 0; i < 4; ++i) {
        int idx = base + i;
        v[i] = (idx < NNODES) ? cnt[idx] : 0;
        s += v[i];
    }
    sd[t] = s;
    __syncthreads();
    for (int off = 1; off < 256; off <<= 1) {
        int val = (t >= off) ? sd[t - off] : 0;
        __syncthreads();
        sd[t] += val;
        __syncthreads();
    }
    int run = sd[t] - s + bsums[b];
#pragma unroll
    for (int i = 0; i < 4; ++i) {
        int idx = base + i;
        if (idx < NNODES) {
            rowptr[idx] = run;
            pos[idx] = run;
            run += v[i];
        }
    }
}

__global__ __launch_bounds__(256) void k_fill(const int* __restrict__ ei, int* __restrict__ pos,
                                              int* __restrict__ elist) {
    int e = blockIdx.x * 256 + threadIdx.x;
    if (e >= NEDGES) return;
    int src = ei[e];
    int dst = ei[NEDGES + e];
    int p = atomicAdd(&pos[dst], 1);
    elist[p] = src;
}

// ---------------- fused gather-aggregate + BN stats ----------------
// 512 threads = 8 waves, 64 nodes/block (8 nodes/wave, serial, chains independent).
// Gathered bf16 rows land in a swizzled LDS tile; one barrier; coalesced bufb write;
// then all 8 waves MFMA the 64x128 tile against W1 for per-column S,Q (b1 cancels).
__global__ __launch_bounds__(512, 8) void k_aggstats(const short* __restrict__ xb,
                                                     const int* __restrict__ rowptr,
                                                     const int* __restrict__ elist,
                                                     const short* __restrict__ W1pk,
                                                     short* __restrict__ bufb,
                                                     float* __restrict__ stats) {
    __shared__ __align__(16) short tile[64 * 128];  // 16KB, swizzled rows
    __shared__ float Sred[2][2][128];               // [s/q][rowgroup][col]

    int t = threadIdx.x, w = t >> 6, lane = t & 63;
    int sub = lane & 31, half = lane >> 5;
    int node0 = blockIdx.x * 64;
    const uint2* xr = (const uint2*)xb;

    // one coalesced rowptr read covers this wave's 8 nodes (9 entries via lanes 0..8)
    int ridx = node0 + w * 8 + min(lane, 8);
    int vr = rowptr[min(ridx, NNODES)];

#pragma unroll
    for (int i = 0; i < 8; ++i) {
        int beg = __shfl(vr, i);
        int end = __shfl(vr, i + 1);
        int n = node0 + w * 8 + i;
        float a0 = 0.f, a1 = 0.f, a2 = 0.f, a3 = 0.f;
        if (n < NNODES) {
            int total = end - beg + 1;
            for (int base = 0; base < total; base += 64) {
                int j = base + lane;
                int ej = NNODES;  // zero row
                if (j < total) ej = (j == 0) ? n : elist[beg + j - 1];
                int cnt = min(64, total - base);
                int pairs = (cnt + 1) >> 1;
                for (int ii = 0; ii < pairs; ii += 4) {
                    int j0 = 2 * ii + half;
                    int r0 = __shfl(ej, j0);
                    int r1 = __shfl(ej, j0 + 2);
                    int r2 = __shfl(ej, j0 + 4);
                    int r3 = __shfl(ej, j0 + 6);
                    uint2 v0 = xr[(size_t)r0 * 32 + sub];
                    uint2 v1 = xr[(size_t)r1 * 32 + sub];
                    uint2 v2 = xr[(size_t)r2 * 32 + sub];
                    uint2 v3 = xr[(size_t)r3 * 32 + sub];
                    a0 += b2f((short)(v0.x & 0xFFFF)) + b2f((short)(v1.x & 0xFFFF)) +
                          b2f((short)(v2.x & 0xFFFF)) + b2f((short)(v3.x & 0xFFFF));
                    a1 += b2f((short)(v0.x >> 16)) + b2f((short)(v1.x >> 16)) +
                          b2f((short)(v2.x >> 16)) + b2f((short)(v3.x >> 16));
                    a2 += b2f((short)(v0.y & 0xFFFF)) + b2f((short)(v1.y & 0xFFFF)) +
                          b2f((short)(v2.y & 0xFFFF)) + b2f((short)(v3.y & 0xFFFF));
                    a3 += b2f((short)(v0.y >> 16)) + b2f((short)(v1.y >> 16)) +
                          b2f((short)(v2.y >> 16)) + b2f((short)(v3.y >> 16));
                }
            }
        }
        a0 += __shfl_xor(a0, 32);
        a1 += __shfl_xor(a1, 32);
        a2 += __shfl_xor(a2, 32);
        a3 += __shfl_xor(a3, 32);
        if (half == 0) {
            int row = w * 8 + i;
            int b8 = sub * 8;
            int off = swz(row, b8 & ~15) + (b8 & 8);
            uint2 o;
            o.x = packbf(a0, a1);
            o.y = packbf(a2, a3);
            *(uint2*)((char*)tile + off) = o;
        }
    }
    __syncthreads();

    // coalesced bufb write from LDS: each thread two 16B chunks of one row
    {
        int row = t >> 3, chunk = t & 7;
        int gr = node0 + row;
        if (gr < NNODES) {
            bf16x8 c0 = *(const bf16x8*)((char*)tile + swz(row, chunk * 32));
            bf16x8 c1 = *(const bf16x8*)((char*)tile + swz(row, chunk * 32 + 16));
            *(bf16x8*)(bufb + (size_t)gr * 128 + chunk * 16) = c0;
            *(bf16x8*)(bufb + (size_t)gr * 128 + chunk * 16 + 8) = c1;
        }
    }

    // stats MFMA: wave w -> rowgroup rg = w&1 (32 rows), colgroup cg = w>>1 (32 cols)
    {
        int lr = lane & 15, hi = lane >> 4;
        int rg = w & 1, cg = w >> 1;
        f32x4 acc[2][2];
#pragma unroll
        for (int r = 0; r < 2; ++r)
#pragma unroll
            for (int c = 0; c < 2; ++c) acc[r][c] = (f32x4){0.f, 0.f, 0.f, 0.f};
#pragma unroll
        for (int kb = 0; kb < 4; ++kb) {
            int kbyte = kb * 64 + hi * 16;
            bf16x8 af[2], bw[2];
#pragma unroll
            for (int r = 0; r < 2; ++r)
                af[r] = *(const bf16x8*)((char*)tile + swz(rg * 32 + r * 16 + lr, kbyte));
#pragma unroll
            for (int c = 0; c < 2; ++c)
                bw[c] = *(const bf16x8*)(W1pk + (((cg * 2 + c) * 4 + kb) * 64 + lane) * 8);
#pragma unroll
            for (int r = 0; r < 2; ++r)
#pragma unroll
                for (int c = 0; c < 2; ++c) acc[r][c] = MFMA16(af[r], bw[c], acc[r][c]);
        }
        // zero LDS rows for invalid nodes -> zero contributions; no guard needed
        float s[2], q[2];
#pragma unroll
        for (int c = 0; c < 2; ++c) { s[c] = 0.f; q[c] = 0.f; }
#pragma unroll
        for (int c = 0; c < 2; ++c)
#pragma unroll
            for (int r = 0; r < 2; ++r)
#pragma unroll
                for (int rr = 0; rr < 4; ++rr) {
                    float v = acc[r][c][rr];
                    s[c] += v;
                    q[c] += v * v;
                }
#pragma unroll
        for (int c = 0; c < 2; ++c) {
            s[c] += __shfl_xor(s[c], 16); s[c] += __shfl_xor(s[c], 32);
            q[c] += __shfl_xor(q[c], 16); q[c] += __shfl_xor(q[c], 32);
        }
        if (lane < 16) {
#pragma unroll
            for (int c = 0; c < 2; ++c) {
                int col = (cg * 2 + c) * 16 + lane;
                Sred[0][rg][col] = s[c];
                Sred[1][rg][col] = q[c];
            }
        }
    }
    __syncthreads();
    if (t < 128) {
        atomicAdd(stats + t, Sred[0][0][t] + Sred[0][1][t]);
        atomicAdd(stats + 128 + t, Sred[1][0][t] + Sred[1][1][t]);
    }
}

// ---------------- fused MLP, 32 nodes/wave, LDS-staged weights ----------------
__global__ __launch_bounds__(256, 4) void k_mlp(const short* __restrict__ bufb,
                                                const float* __restrict__ stats,
                                                const float* __restrict__ gamma,
                                                const float* __restrict__ beta,
                                                const short* __restrict__ Wt,
                                                const float* __restrict__ b2,
                                                const float* __restrict__ bm1,
                                                const float* __restrict__ bm2,
                                                float* __restrict__ out) {
    __shared__ __align__(16) short wbuf[16384];  // 32KB weight stage
    __shared__ float scl[3][128], shf[3][128], bm2s[64];

    int t = threadIdx.x, w = t >> 6, l = t & 63;
    int lr = l & 15, hi = l >> 4;
    size_t node0 = (size_t)blockIdx.x * 128 + w * 32;

    stage_lds(Wt, wbuf, w, l, 8);
    if (t < 128) {
        float mean = stats[t] * (1.0f / NNODES);
        float var = fmaxf(stats[128 + t] * (1.0f / NNODES) - mean * mean, 0.0f);
        float inv = rsqrtf(var + 1e-5f);
        float sc = gamma[t] * inv;
        scl[0][t] = sc;
        shf[0][t] = beta[t] - mean * sc;  // b1 cancels in batch-stats BN
        scl[1][t] = 1.0f;
        shf[1][t] = b2[t];
        scl[2][t] = 1.0f;
        shf[2][t] = bm1[t];
    }
    if (t < 64) bm2s[t] = bm2[t];

    bf16x8 bvA[4], bvB[4];
#pragma unroll
    for (int kt = 0; kt < 4; ++kt) {
        bvA[kt] = *(const bf16x8*)(bufb + (node0 + lr) * 128 + kt * 32 + hi * 8);
        bvB[kt] = *(const bf16x8*)(bufb + (node0 + 16 + lr) * 128 + kt * 32 + hi * 8);
    }
    __syncthreads();

    unsigned pwA[8][2], pwB[8][2];

    for (int g = 0; g < 3; ++g) {
#pragma unroll
        for (int ch = 0; ch < 2; ++ch) {
            f32x4 aA[4], aB[4];
#pragma unroll
            for (int cc = 0; cc < 4; ++cc) {
                aA[cc] = (f32x4){0.f, 0.f, 0.f, 0.f};
                aB[cc] = (f32x4){0.f, 0.f, 0.f, 0.f};
            }
#pragma unroll
            for (int kt = 0; kt < 4; ++kt) {
                bf16x8 wv[4];
#pragma unroll
                for (int cc = 0; cc < 4; ++cc)
                    wv[cc] = *(const bf16x8*)(wbuf + ((((ch * 4 + cc) * 4) + kt) * 64 + l) * 8);
#pragma unroll
                for (int cc = 0; cc < 4; ++cc) {
                    aA[cc] = MFMA16(wv[cc], bvA[kt], aA[cc]);
                    aB[cc] = MFMA16(wv[cc], bvB[kt], aB[cc]);
                }
            }
#pragma unroll
            for (int cc = 0; cc < 4; ++cc) {
                int ct = ch * 4 + cc;
                int c0 = ct * 16 + hi * 4;
                float4 s4 = *(const float4*)&scl[g][c0];
                float4 h4 = *(const float4*)&shf[g][c0];
                pwA[ct][0] = packbf(fmaxf(aA[cc][0] * s4.x + h4.x, 0.f),
                                    fmaxf(aA[cc][1] * s4.y + h4.y, 0.f));
                pwA[ct][1] = packbf(fmaxf(aA[cc][2] * s4.z + h4.z, 0.f),
                                    fmaxf(aA[cc][3] * s4.w + h4.w, 0.f));
                pwB[ct][0] = packbf(fmaxf(aB[cc][0] * s4.x + h4.x, 0.f),
                                    fmaxf(aB[cc][1] * s4.y + h4.y, 0.f));
                pwB[ct][1] = packbf(fmaxf(aB[cc][2] * s4.z + h4.z, 0.f),
                                    fmaxf(aB[cc][3] * s4.w + h4.w, 0.f));
            }
        }
        __syncthreads();
        if (g < 2) stage_lds(Wt + (g + 1) * 16384, wbuf, w, l, 8);
        else       stage_lds(Wt + 49152, wbuf, w, l, 4);  // Wm2, 16KB

        {
            int h2 = hi >> 1, h1 = hi & 1;
#pragma unroll
            for (int kt = 0; kt < 4; ++kt) {
                unsigned nwA[4], nwB[4];
#pragma unroll
                for (int jp = 0; jp < 4; ++jp) {
                    int srcl = (2 * h1 + (jp >> 1)) * 16 + lr;
                    unsigned veA = (unsigned)__shfl((int)pwA[2 * kt][jp & 1], srcl);
                    unsigned voA = (unsigned)__shfl((int)pwA[2 * kt + 1][jp & 1], srcl);
                    unsigned veB = (unsigned)__shfl((int)pwB[2 * kt][jp & 1], srcl);
                    unsigned voB = (unsigned)__shfl((int)pwB[2 * kt + 1][jp & 1], srcl);
                    nwA[jp] = h2 ? voA : veA;
                    nwB[jp] = h2 ? voB : veB;
                }
                u32x4 uqA = (u32x4){nwA[0], nwA[1], nwA[2], nwA[3]};
                u32x4 uqB = (u32x4){nwB[0], nwB[1], nwB[2], nwB[3]};
                bvA[kt] = __builtin_bit_cast(bf16x8, uqA);
                bvB[kt] = __builtin_bit_cast(bf16x8, uqB);
            }
        }
        __syncthreads();
    }

#pragma unroll
    for (int ct = 0; ct < 4; ++ct) {
        f32x4 aA = (f32x4){0.f, 0.f, 0.f, 0.f};
        f32x4 aB = (f32x4){0.f, 0.f, 0.f, 0.f};
#pragma unroll
        for (int kt = 0; kt < 4; ++kt) {
            bf16x8 wv = *(const bf16x8*)(wbuf + ((ct * 4 + kt) * 64 + l) * 8);
            aA = MFMA16(bvA[kt], wv, aA);
            aB = MFMA16(bvB[kt], wv, aB);
        }
        float bias = bm2s[ct * 16 + lr];
#pragma unroll
        for (int rr = 0; rr < 4; ++rr) {
            size_t growA = node0 + hi * 4 + rr;
            size_t growB = node0 + 16 + hi * 4 + rr;
            if (growA < NNODES) out[growA * 64 + ct * 16 + lr] = aA[rr] + bias;
            if (growB < NNODES) out[growB * 64 + ct * 16 + lr] = aB[rr] + bias;
        }
    }
}

// ---------------- launch ----------------
extern "C" void kernel_launch(void* const* d_in, const int* in_sizes, int n_in,
                              void* d_out, int out_size, void* d_ws, size_t ws_size,
                              hipStream_t stream) {
    const float* x     = (const float*)d_in[0];
    const int*   ei    = (const int*)d_in[1];
    const float* W1    = (const float*)d_in[2];
    const float* gamma = (const float*)d_in[4];
    const float* beta  = (const float*)d_in[5];
    const float* W2    = (const float*)d_in[6];
    const float* b2    = (const float*)d_in[7];
    const float* Wm1   = (const float*)d_in[8];
    const float* bm1   = (const float*)d_in[9];
    const float* Wm2   = (const float*)d_in[10];
    const float* bm2   = (const float*)d_in[11];
    float* out = (float*)d_out;

    char* ws = (char*)d_ws;
    short* xb    = (short*)ws;                           // (N+1)*128 bf16 (last row zeros)
    short* bufb  = xb + (size_t)(NNODES + 1) * 128;      // (N+128)*128 bf16 (tail padding)
    short* Wt    = bufb + (size_t)(NNODES + 128) * 128;  // 57344 bf16 packed fragments
    float* stats = (float*)(Wt + 57344);                 // 256 f32
    int* rowptr  = (int*)(stats + 256);                  // N+1
    int* pos     = rowptr + (NNODES + 1);                // N
    int* elist   = pos + NNODES;                         // E
    int* bsums   = elist + NEDGES;                       // 128

    int gE = (NEDGES + 255) / 256;
    int gPrep = ((NNODES + 1) * 16 + 255) / 256;

    k_prep<<<gPrep, 256, 0, stream>>>(x, W1, W2, Wm1, Wm2, xb, Wt, pos, stats);
    k_hist<<<gE, 256, 0, stream>>>(ei, pos);
    k_scan1<<<SCAN_NB, 256, 0, stream>>>(pos, bsums);
    k_scan2<<<1, 64, 0, stream>>>(bsums, rowptr);
    k_scan3<<<SCAN_NB, 256, 0, stream>>>(pos, bsums, rowptr, pos);
    k_fill<<<gE, 256, 0, stream>>>(ei, pos, elist);

    int gAgg = (NNODES + 63) / 64;
    k_aggstats<<<gAgg, 512, 0, stream>>>(xb, rowptr, elist, Wt, bufb, stats);

    int nblkM = (NNODES + 127) / 128;
    k_mlp<<<nblkM, 256, 0, stream>>>(bufb, stats, gamma, beta, Wt, b2, bm1, bm2, out);
}